// Round 2
// baseline (1093.362 us; speedup 1.0000x reference)
//
#include <hip/hip_runtime.h>
#include <math.h>

#define NN 50000
#define NE 60000
#define FIN 32
#define DIM 64
#define NGB 256   // graphs in batch

__device__ __forceinline__ float rl(float v, int lane) {
    return __int_as_float(__builtin_amdgcn_readlane(__float_as_int(v), lane));
}
__device__ __forceinline__ float sigm(float x) { return 1.f / (1.f + expf(-x)); }

// pack two f32 as bf16 (RTN) into one u32: a -> low16, b -> high16
__device__ __forceinline__ unsigned int pk2(float a, float b) {
    unsigned int ua = __float_as_uint(a);
    unsigned int ub = __float_as_uint(b);
    ua = (ua + 0x7FFFu + ((ua >> 16) & 1u)) >> 16;
    ub = (ub + 0x7FFFu + ((ub >> 16) & 1u)) & 0xFFFF0000u;
    return ua | ub;
}
__device__ __forceinline__ float lo16(unsigned int w) { return __uint_as_float(w << 16); }
__device__ __forceinline__ float hi16(unsigned int w) { return __uint_as_float(w & 0xFFFF0000u); }

// ---------------- precompute: W[i*64+o] = (relu(nn1_w + nn1_b) @ nn2_w^T + nn2_b)
__global__ void k_precompute_W(const float* __restrict__ nn1_w, const float* __restrict__ nn1_b,
                               const float* __restrict__ nn2_w, const float* __restrict__ nn2_b,
                               float* __restrict__ W) {
    __shared__ float t[64];
    int tid = threadIdx.x;
    if (tid < 64) t[tid] = fmaxf(nn1_w[tid] + nn1_b[tid], 0.f);
    __syncthreads();
    int k = blockIdx.x * blockDim.x + tid;   // 0..4095
    float acc = nn2_b[k];
    #pragma unroll
    for (int j = 0; j < 64; ++j) acc += t[j] * nn2_w[k * 64 + j];
    W[k] = acc;
}

// ---------------- transpose LSTM weights for coalesced gate dots
__global__ void k_transpose_lstm(const float* __restrict__ wih, const float* __restrict__ whh,
                                 float* __restrict__ wihT, float* __restrict__ whhT) {
    int p = blockIdx.x * 256 + threadIdx.x;
    if (p < 256 * 128) { int o = p >> 7, k = p & 127; wihT[k * 256 + o] = wih[p]; }
    if (p < 256 * 64)  { int o = p >> 6, k = p & 63;  whhT[k * 256 + o] = whh[p]; }
}

// ---------------- degree (over dst) + per-graph node counts
__global__ void k_deg_cnt(const int* __restrict__ ei, const int* __restrict__ batch,
                          float* __restrict__ deg, int* __restrict__ cnt) {
    int i = blockIdx.x * 256 + threadIdx.x;
    if (i < NE) atomicAdd(&deg[ei[NE + i]], 1.0f);
    if (i < NN) atomicAdd(&cnt[batch[i]], 1);
}

// ---------------- exclusive prefix scan of cnt[256] -> starts[256]
__global__ void k_scan(const int* __restrict__ cnt, int* __restrict__ starts) {
    __shared__ int sc[256];
    int t = threadIdx.x;
    int c = cnt[t];
    sc[t] = c;
    __syncthreads();
    for (int off = 1; off < 256; off <<= 1) {
        int v = (t >= off) ? sc[t - off] : 0;
        __syncthreads();
        sc[t] += v;
        __syncthreads();
    }
    starts[t] = sc[t] - c;
}

// ---------------- lin0: h = relu(x @ lin0_w^T + b), 64 lanes per node
__global__ void k_lin0(const float* __restrict__ x, const float* __restrict__ w,
                       const float* __restrict__ b, float* __restrict__ h) {
    __shared__ float wT[FIN * 64];   // wT[k*64+o] = w[o*32+k]
    int tid = threadIdx.x;
    for (int p = tid; p < FIN * 64; p += 256) {
        int o = p >> 5, k = p & 31;
        wT[k * 64 + o] = w[p];
    }
    __syncthreads();
    int l = tid & 63;
    int n = blockIdx.x * 4 + (tid >> 6);
    if (n >= NN) return;
    float xv = x[n * FIN + (l & 31)];
    float acc = b[l];
    #pragma unroll
    for (int k = 0; k < FIN; ++k) {
        float xk = rl(xv, k);
        acc += xk * wT[k * 64 + l];
    }
    h[n * 64 + l] = fmaxf(acc, 0.f);
}

// ---------------- scatter: agg[dst] += h[src]  (64 lanes per edge)
__global__ void k_scatter(const int* __restrict__ ei, const float* __restrict__ h,
                          float* __restrict__ agg) {
    int gid = blockIdx.x * 256 + threadIdx.x;
    int e = gid >> 6, l = gid & 63;
    if (e >= NE) return;
    int s = ei[e], d = ei[NE + e];
    atomicAdd(&agg[d * 64 + l], h[s * 64 + l]);
}

// ---------------- fused conv(W matvec)+GRU node update. static LDS = 64 KB.
__global__ void __launch_bounds__(1024) k_update(
    const float* __restrict__ agg, const float* __restrict__ deg, const float* __restrict__ W,
    const float* __restrict__ conv_b, const float* __restrict__ wih, const float* __restrict__ whh,
    const float* __restrict__ bih, const float* __restrict__ bhh, float* __restrict__ h) {
    __shared__ float Wl[4096];              // Wl[j*64+l] = W[j*64+l]                (16 KB, f32)
    __shared__ unsigned int gw[12288];      // gw[(g*64+i)*64+l] = pk2(wih, whh)     (48 KB, bf16x2)
    int tid = threadIdx.x;
    for (int p = tid; p < 4096; p += 1024) Wl[p] = W[p];
    for (int p = tid; p < 12288; p += 1024) {
        int o = p >> 6, i = p & 63;         // o = g*64+l (weight row), i = col
        int g = o >> 6, l = o & 63;
        gw[(g * 64 + i) * 64 + l] = pk2(wih[p], whh[p]);
    }
    __syncthreads();
    int l = tid & 63;
    int wave = blockIdx.x * (blockDim.x >> 6) + (tid >> 6);
    int nwaves = gridDim.x * (blockDim.x >> 6);
    float cb = conv_b[l];
    float bi0 = bih[l], bi1 = bih[64 + l], bi2 = bih[128 + l];
    float bh0 = bhh[l], bh1 = bhh[64 + l], bh2 = bhh[128 + l];

    for (int t0 = wave * 4; t0 < NN; t0 += nwaves * 4) {
        float aggv[4], hv[4];
        #pragma unroll
        for (int r = 0; r < 4; ++r) {
            int n = t0 + r;
            if (n < NN) {
                float d = deg[n];
                float inv = d > 0.f ? 1.f / d : 0.f;
                aggv[r] = agg[n * 64 + l] * inv;
                hv[r]   = h[n * 64 + l];
            } else { aggv[r] = 0.f; hv[r] = 0.f; }
        }
        // stage A: m = relu(aggv @ W + conv_b)
        float mv[4] = {0.f, 0.f, 0.f, 0.f};
        #pragma unroll 8
        for (int j = 0; j < 64; ++j) {
            float wj = Wl[j * 64 + l];
            #pragma unroll
            for (int r = 0; r < 4; ++r) mv[r] += rl(aggv[r], j) * wj;
        }
        #pragma unroll
        for (int r = 0; r < 4; ++r) mv[r] = fmaxf(mv[r] + cb, 0.f);
        // stage B: gi = m @ Wih^T, gh = h @ Whh^T  (packed bf16 weights)
        float ai[4][3], ah[4][3];
        #pragma unroll
        for (int r = 0; r < 4; ++r)
            #pragma unroll
            for (int g = 0; g < 3; ++g) { ai[r][g] = 0.f; ah[r][g] = 0.f; }
        #pragma unroll 4
        for (int i = 0; i < 64; ++i) {
            float sm[4], sh[4];
            #pragma unroll
            for (int r = 0; r < 4; ++r) { sm[r] = rl(mv[r], i); sh[r] = rl(hv[r], i); }
            #pragma unroll
            for (int g = 0; g < 3; ++g) {
                unsigned int w = gw[(g * 64 + i) * 64 + l];
                float wi = lo16(w), wh = hi16(w);
                #pragma unroll
                for (int r = 0; r < 4; ++r) { ai[r][g] += sm[r] * wi; ah[r][g] += sh[r] * wh; }
            }
        }
        #pragma unroll
        for (int r = 0; r < 4; ++r) {
            int n = t0 + r;
            if (n < NN) {
                float rg = sigm(ai[r][0] + bi0 + ah[r][0] + bh0);
                float zg = sigm(ai[r][1] + bi1 + ah[r][1] + bh1);
                float ng = tanhf(ai[r][2] + bi2 + rg * (ah[r][2] + bh2));
                h[n * 64 + l] = (1.f - zg) * ng + zg * hv[r];
            }
        }
    }
}

// ---------------- Set2Set LSTM step (fused gates+state). 4 graphs / block.
__global__ void k_lstm(const float* __restrict__ qstar, const float* __restrict__ wihT,
                       const float* __restrict__ whhT, const float* __restrict__ bih,
                       const float* __restrict__ bhh, float* __restrict__ hl, float* __restrict__ cl) {
    int tid = threadIdx.x;
    int row = tid >> 6, o = tid & 63;
    int b = blockIdx.x * 4 + row;
    const float* qs = qstar + b * 128;
    float hlv = hl[b * 64 + o];
    float clv = cl[b * 64 + o];
    float a0 = bih[o]       + bhh[o];
    float a1 = bih[64 + o]  + bhh[64 + o];
    float a2 = bih[128 + o] + bhh[128 + o];
    float a3 = bih[192 + o] + bhh[192 + o];
    for (int k = 0; k < 128; ++k) {
        float q = qs[k];
        a0 += q * wihT[k * 256 + o];
        a1 += q * wihT[k * 256 + 64 + o];
        a2 += q * wihT[k * 256 + 128 + o];
        a3 += q * wihT[k * 256 + 192 + o];
    }
    for (int k = 0; k < 64; ++k) {
        float hq = rl(hlv, k);   // recurrence read from registers, no RAW race
        a0 += hq * whhT[k * 256 + o];
        a1 += hq * whhT[k * 256 + 64 + o];
        a2 += hq * whhT[k * 256 + 128 + o];
        a3 += hq * whhT[k * 256 + 192 + o];
    }
    float c = sigm(a1) * clv + sigm(a0) * tanhf(a2);
    cl[b * 64 + o] = c;
    hl[b * 64 + o] = sigm(a3) * tanhf(c);
}

// ---------------- segment softmax + weighted sum; one wave per graph
__global__ void k_attn(const float* __restrict__ h, const float* __restrict__ hl,
                       const int* __restrict__ starts, const int* __restrict__ cnt,
                       float* __restrict__ qstar) {
    int b = blockIdx.x;
    int l = threadIdx.x;
    float hld = hl[b * 64 + l];
    int s = starts[b], e = s + cnt[b];
    float m = -1e30f;
    for (int n = s; n < e; ++n) {
        float v = h[n * 64 + l] * hld;
        #pragma unroll
        for (int off = 32; off; off >>= 1) v += __shfl_xor(v, off, 64);
        m = fmaxf(m, v);
    }
    float ssum = 0.f, racc = 0.f;
    for (int n = s; n < e; ++n) {
        float hv = h[n * 64 + l];
        float v = hv * hld;
        #pragma unroll
        for (int off = 32; off; off >>= 1) v += __shfl_xor(v, off, 64);
        float a = expf(v - m);
        ssum += a;
        racc += a * hv;
    }
    qstar[b * 128 + l] = hld;
    qstar[b * 128 + 64 + l] = racc / (ssum + 1e-16f);
}

extern "C" void kernel_launch(void* const* d_in, const int* in_sizes, int n_in,
                              void* d_out, int out_size, void* d_ws, size_t ws_size,
                              hipStream_t stream) {
    const float* x      = (const float*)d_in[0];
    const int*   ei     = (const int*)  d_in[1];
    const int*   batch  = (const int*)  d_in[2];
    const float* lin0_w = (const float*)d_in[3];
    const float* lin0_b = (const float*)d_in[4];
    const float* nn1_w  = (const float*)d_in[5];
    const float* nn1_b  = (const float*)d_in[6];
    const float* nn2_w  = (const float*)d_in[7];
    const float* nn2_b  = (const float*)d_in[8];
    const float* conv_b = (const float*)d_in[9];
    const float* gwih   = (const float*)d_in[10];
    const float* gwhh   = (const float*)d_in[11];
    const float* gbih   = (const float*)d_in[12];
    const float* gbhh   = (const float*)d_in[13];
    const float* lwih   = (const float*)d_in[14];
    const float* lwhh   = (const float*)d_in[15];
    const float* lbih   = (const float*)d_in[16];
    const float* lbhh   = (const float*)d_in[17];

    float* qstar = (float*)d_out;                 // [256*128]
    float* h     = (float*)d_out + NGB * 128;     // [N*64] == feat_map

    float* ws     = (float*)d_ws;
    float* W      = ws;                         // 4096
    float* agg    = ws + 4096;                  // N*64
    float* deg    = agg + NN * 64;              // N
    int*   cnt    = (int*)(deg + NN);           // 256
    int*   starts = cnt + 256;                  // 256
    float* hl     = (float*)(starts + 256);     // 256*64
    float* cl     = hl + NGB * 64;              // 256*64
    float* wihT   = cl + NGB * 64;              // 128*256
    float* whhT   = wihT + 128 * 256;           // 64*256

    hipMemsetAsync(deg, 0, NN * sizeof(float), stream);
    hipMemsetAsync(cnt, 0, 256 * sizeof(int), stream);
    hipMemsetAsync(hl, 0, 2 * NGB * 64 * sizeof(float), stream);   // hl + cl
    hipMemsetAsync(qstar, 0, NGB * 128 * sizeof(float), stream);

    k_precompute_W<<<16, 256, 0, stream>>>(nn1_w, nn1_b, nn2_w, nn2_b, W);
    k_transpose_lstm<<<128, 256, 0, stream>>>(lwih, lwhh, wihT, whhT);
    k_deg_cnt<<<(NE + 255) / 256, 256, 0, stream>>>(ei, batch, deg, cnt);
    k_scan<<<1, 256, 0, stream>>>(cnt, starts);
    k_lin0<<<(NN + 3) / 4, 256, 0, stream>>>(x, lin0_w, lin0_b, h);

    for (int it = 0; it < 3; ++it) {
        hipMemsetAsync(agg, 0, NN * 64 * sizeof(float), stream);
        k_scatter<<<(NE * 64 + 255) / 256, 256, 0, stream>>>(ei, h, agg);
        k_update<<<512, 1024, 0, stream>>>(agg, deg, W, conv_b, gwih, gwhh, gbih, gbhh, h);
    }
    for (int st = 0; st < 3; ++st) {
        k_lstm<<<64, 256, 0, stream>>>(qstar, wihT, whhT, lbih, lbhh, hl, cl);
        k_attn<<<256, 64, 0, stream>>>(h, hl, starts, cnt, qstar);
    }
}

// Round 3
// 705.825 us; speedup vs baseline: 1.5491x; 1.5491x over previous
//
#include <hip/hip_runtime.h>
#include <math.h>

#define NN 50000
#define NE 60000
#define FIN 32
#define DIM 64
#define NGB 256   // graphs in batch

__device__ __forceinline__ float rl(float v, int lane) {
    return __int_as_float(__builtin_amdgcn_readlane(__float_as_int(v), lane));
}
__device__ __forceinline__ float sigm(float x) { return 1.f / (1.f + expf(-x)); }

// pack two f32 as bf16 (RTN) into one u32: a -> low16, b -> high16
__device__ __forceinline__ unsigned int pk2(float a, float b) {
    unsigned int ua = __float_as_uint(a);
    unsigned int ub = __float_as_uint(b);
    ua = (ua + 0x7FFFu + ((ua >> 16) & 1u)) >> 16;
    ub = (ub + 0x7FFFu + ((ub >> 16) & 1u)) & 0xFFFF0000u;
    return ua | ub;
}
__device__ __forceinline__ float lo16(unsigned int w) { return __uint_as_float(w << 16); }
__device__ __forceinline__ float hi16(unsigned int w) { return __uint_as_float(w & 0xFFFF0000u); }

// ---------------- precompute: W[i*64+o] = (relu(nn1_w + nn1_b) @ nn2_w^T + nn2_b)
__global__ void k_precompute_W(const float* __restrict__ nn1_w, const float* __restrict__ nn1_b,
                               const float* __restrict__ nn2_w, const float* __restrict__ nn2_b,
                               float* __restrict__ W) {
    __shared__ float t[64];
    int tid = threadIdx.x;
    if (tid < 64) t[tid] = fmaxf(nn1_w[tid] + nn1_b[tid], 0.f);
    __syncthreads();
    int k = blockIdx.x * blockDim.x + tid;   // 0..4095
    float acc = nn2_b[k];
    #pragma unroll
    for (int j = 0; j < 64; ++j) acc += t[j] * nn2_w[k * 64 + j];
    W[k] = acc;
}

// ---------------- transpose LSTM weights for coalesced gate dots
__global__ void k_transpose_lstm(const float* __restrict__ wih, const float* __restrict__ whh,
                                 float* __restrict__ wihT, float* __restrict__ whhT) {
    int p = blockIdx.x * 256 + threadIdx.x;
    if (p < 256 * 128) { int o = p >> 7, k = p & 127; wihT[k * 256 + o] = wih[p]; }
    if (p < 256 * 64)  { int o = p >> 6, k = p & 63;  whhT[k * 256 + o] = whh[p]; }
}

// ---------------- degree (over dst) + per-graph node counts
__global__ void k_deg_cnt(const int* __restrict__ ei, const int* __restrict__ batch,
                          float* __restrict__ deg, int* __restrict__ cnt) {
    int i = blockIdx.x * 256 + threadIdx.x;
    if (i < NE) atomicAdd(&deg[ei[NE + i]], 1.0f);
    if (i < NN) atomicAdd(&cnt[batch[i]], 1);
}

// ---------------- exclusive prefix scan of cnt[256] -> starts[256]
__global__ void k_scan(const int* __restrict__ cnt, int* __restrict__ starts) {
    __shared__ int sc[256];
    int t = threadIdx.x;
    int c = cnt[t];
    sc[t] = c;
    __syncthreads();
    for (int off = 1; off < 256; off <<= 1) {
        int v = (t >= off) ? sc[t - off] : 0;
        __syncthreads();
        sc[t] += v;
        __syncthreads();
    }
    starts[t] = sc[t] - c;
}

// ---------------- lin0: h = relu(x @ lin0_w^T + b), 64 lanes per node
__global__ void k_lin0(const float* __restrict__ x, const float* __restrict__ w,
                       const float* __restrict__ b, float* __restrict__ h) {
    __shared__ float wT[FIN * 64];   // wT[k*64+o] = w[o*32+k]
    int tid = threadIdx.x;
    for (int p = tid; p < FIN * 64; p += 256) {
        int o = p >> 5, k = p & 31;
        wT[k * 64 + o] = w[p];
    }
    __syncthreads();
    int l = tid & 63;
    int n = blockIdx.x * 4 + (tid >> 6);
    if (n >= NN) return;
    float xv = x[n * FIN + (l & 31)];
    float acc = b[l];
    #pragma unroll
    for (int k = 0; k < FIN; ++k) {
        float xk = rl(xv, k);
        acc += xk * wT[k * 64 + l];
    }
    h[n * 64 + l] = fmaxf(acc, 0.f);
}

// ---------------- scatter: agg[dst] += h[src]  (64 lanes per edge)
__global__ void k_scatter(const int* __restrict__ ei, const float* __restrict__ h,
                          float* __restrict__ agg) {
    int gid = blockIdx.x * 256 + threadIdx.x;
    int e = gid >> 6, l = gid & 63;
    if (e >= NE) return;
    int s = ei[e], d = ei[NE + e];
    atomicAdd(&agg[d * 64 + l], h[s * 64 + l]);
}

// ---------------- fused conv(W matvec)+GRU node update. static LDS = 64 KB.
// Also re-zeroes agg after reading (each n visited exactly once) so the
// per-iteration memset dispatch is not needed.
__global__ void __launch_bounds__(1024) k_update(
    const float* __restrict__ agg, const float* __restrict__ deg, const float* __restrict__ W,
    const float* __restrict__ conv_b, const float* __restrict__ wih, const float* __restrict__ whh,
    const float* __restrict__ bih, const float* __restrict__ bhh, float* __restrict__ h,
    float* __restrict__ aggz) {
    __shared__ float Wl[4096];              // Wl[j*64+l] = W[j*64+l]                (16 KB, f32)
    __shared__ unsigned int gw[12288];      // gw[(g*64+i)*64+l] = pk2(wih, whh)     (48 KB, bf16x2)
    int tid = threadIdx.x;
    for (int p = tid; p < 4096; p += 1024) Wl[p] = W[p];
    for (int p = tid; p < 12288; p += 1024) {
        int o = p >> 6, i = p & 63;         // o = g*64+l (weight row), i = col
        int g = o >> 6, l = o & 63;
        gw[(g * 64 + i) * 64 + l] = pk2(wih[p], whh[p]);
    }
    __syncthreads();
    int l = tid & 63;
    int wave = blockIdx.x * (blockDim.x >> 6) + (tid >> 6);
    int nwaves = gridDim.x * (blockDim.x >> 6);
    float cb = conv_b[l];
    float bi0 = bih[l], bi1 = bih[64 + l], bi2 = bih[128 + l];
    float bh0 = bhh[l], bh1 = bhh[64 + l], bh2 = bhh[128 + l];

    for (int t0 = wave * 4; t0 < NN; t0 += nwaves * 4) {
        float aggv[4], hv[4];
        #pragma unroll
        for (int r = 0; r < 4; ++r) {
            int n = t0 + r;
            if (n < NN) {
                float d = deg[n];
                float inv = d > 0.f ? 1.f / d : 0.f;
                aggv[r] = agg[n * 64 + l] * inv;
                aggz[n * 64 + l] = 0.f;     // pre-zero for next scatter round
                hv[r]   = h[n * 64 + l];
            } else { aggv[r] = 0.f; hv[r] = 0.f; }
        }
        // stage A: m = relu(aggv @ W + conv_b)
        float mv[4] = {0.f, 0.f, 0.f, 0.f};
        #pragma unroll 8
        for (int j = 0; j < 64; ++j) {
            float wj = Wl[j * 64 + l];
            #pragma unroll
            for (int r = 0; r < 4; ++r) mv[r] += rl(aggv[r], j) * wj;
        }
        #pragma unroll
        for (int r = 0; r < 4; ++r) mv[r] = fmaxf(mv[r] + cb, 0.f);
        // stage B: gi = m @ Wih^T, gh = h @ Whh^T  (packed bf16 weights)
        float ai[4][3], ah[4][3];
        #pragma unroll
        for (int r = 0; r < 4; ++r)
            #pragma unroll
            for (int g = 0; g < 3; ++g) { ai[r][g] = 0.f; ah[r][g] = 0.f; }
        #pragma unroll 4
        for (int i = 0; i < 64; ++i) {
            float sm[4], sh[4];
            #pragma unroll
            for (int r = 0; r < 4; ++r) { sm[r] = rl(mv[r], i); sh[r] = rl(hv[r], i); }
            #pragma unroll
            for (int g = 0; g < 3; ++g) {
                unsigned int w = gw[(g * 64 + i) * 64 + l];
                float wi = lo16(w), wh = hi16(w);
                #pragma unroll
                for (int r = 0; r < 4; ++r) { ai[r][g] += sm[r] * wi; ah[r][g] += sh[r] * wh; }
            }
        }
        #pragma unroll
        for (int r = 0; r < 4; ++r) {
            int n = t0 + r;
            if (n < NN) {
                float rg = sigm(ai[r][0] + bi0 + ah[r][0] + bh0);
                float zg = sigm(ai[r][1] + bi1 + ah[r][1] + bh1);
                float ng = tanhf(ai[r][2] + bi2 + rg * (ah[r][2] + bh2));
                h[n * 64 + l] = (1.f - zg) * ng + zg * hv[r];
            }
        }
    }
}

// ---------------- Set2Set LSTM step; one wave per graph, 256 blocks
__global__ void k_lstm(const float* __restrict__ qstar, const float* __restrict__ wihT,
                       const float* __restrict__ whhT, const float* __restrict__ bih,
                       const float* __restrict__ bhh, float* __restrict__ hl, float* __restrict__ cl) {
    int o = threadIdx.x;            // 0..63
    int b = blockIdx.x;             // graph
    const float* qs = qstar + b * 128;
    float hlv = hl[b * 64 + o];
    float clv = cl[b * 64 + o];
    float a0 = bih[o]       + bhh[o];
    float a1 = bih[64 + o]  + bhh[64 + o];
    float a2 = bih[128 + o] + bhh[128 + o];
    float a3 = bih[192 + o] + bhh[192 + o];
    for (int k = 0; k < 128; ++k) {
        float q = qs[k];
        a0 += q * wihT[k * 256 + o];
        a1 += q * wihT[k * 256 + 64 + o];
        a2 += q * wihT[k * 256 + 128 + o];
        a3 += q * wihT[k * 256 + 192 + o];
    }
    for (int k = 0; k < 64; ++k) {
        float hq = rl(hlv, k);   // recurrence read from registers, no RAW race
        a0 += hq * whhT[k * 256 + o];
        a1 += hq * whhT[k * 256 + 64 + o];
        a2 += hq * whhT[k * 256 + 128 + o];
        a3 += hq * whhT[k * 256 + 192 + o];
    }
    float c = sigm(a1) * clv + sigm(a0) * tanhf(a2);
    cl[b * 64 + o] = c;
    hl[b * 64 + o] = sigm(a3) * tanhf(c);
}

// ---------------- e[n] = dot(h[n,:], hl[batch[n],:]) ; wave per node
__global__ void k_dot(const float* __restrict__ h, const float* __restrict__ hl,
                      const int* __restrict__ batch, float* __restrict__ e) {
    int gid = blockIdx.x * 256 + threadIdx.x;
    int n = gid >> 6, l = gid & 63;
    if (n >= NN) return;
    int b = batch[n];
    float v = h[n * 64 + l] * hl[b * 64 + l];
    #pragma unroll
    for (int off = 32; off; off >>= 1) v += __shfl_xor(v, off, 64);
    if (l == 0) e[n] = v;
}

// ---------------- segment softmax + weighted sum; block (4 waves) per graph
__global__ void k_attn2(const float* __restrict__ h, const float* __restrict__ hl,
                        const float* __restrict__ e, const int* __restrict__ starts,
                        const int* __restrict__ cnt, float* __restrict__ qstar) {
    __shared__ float red[8];
    __shared__ float bcast[2];
    __shared__ float acc[4][64];
    int b = blockIdx.x;
    int tid = threadIdx.x;
    int w = tid >> 6, l = tid & 63;
    int s = starts[b], c = cnt[b];
    // phase A: max over e-segment
    float m = -1e30f;
    for (int i = tid; i < c; i += 256) m = fmaxf(m, e[s + i]);
    #pragma unroll
    for (int off = 32; off; off >>= 1) m = fmaxf(m, __shfl_xor(m, off, 64));
    if (l == 0) red[w] = m;
    __syncthreads();
    if (tid == 0) bcast[0] = fmaxf(fmaxf(red[0], red[1]), fmaxf(red[2], red[3]));
    __syncthreads();
    m = bcast[0];
    // phase B: sum of exp
    float ss = 0.f;
    for (int i = tid; i < c; i += 256) ss += expf(e[s + i] - m);
    #pragma unroll
    for (int off = 32; off; off >>= 1) ss += __shfl_xor(ss, off, 64);
    if (l == 0) red[4 + w] = ss;
    __syncthreads();
    if (tid == 0) bcast[1] = red[4] + red[5] + red[6] + red[7];
    __syncthreads();
    float asum = bcast[1];
    // phase C: weighted sum of h rows (wave-striped, coalesced, no shuffles)
    float racc = 0.f;
    for (int i = w; i < c; i += 4) {
        int n = s + i;
        float a = expf(e[n] - m);
        racc += a * h[n * 64 + l];
    }
    acc[w][l] = racc;
    __syncthreads();
    if (w == 0) {
        float tot = acc[0][l] + acc[1][l] + acc[2][l] + acc[3][l];
        qstar[b * 128 + l] = hl[b * 64 + l];
        qstar[b * 128 + 64 + l] = tot / (asum + 1e-16f);
    }
}

extern "C" void kernel_launch(void* const* d_in, const int* in_sizes, int n_in,
                              void* d_out, int out_size, void* d_ws, size_t ws_size,
                              hipStream_t stream) {
    const float* x      = (const float*)d_in[0];
    const int*   ei     = (const int*)  d_in[1];
    const int*   batch  = (const int*)  d_in[2];
    const float* lin0_w = (const float*)d_in[3];
    const float* lin0_b = (const float*)d_in[4];
    const float* nn1_w  = (const float*)d_in[5];
    const float* nn1_b  = (const float*)d_in[6];
    const float* nn2_w  = (const float*)d_in[7];
    const float* nn2_b  = (const float*)d_in[8];
    const float* conv_b = (const float*)d_in[9];
    const float* gwih   = (const float*)d_in[10];
    const float* gwhh   = (const float*)d_in[11];
    const float* gbih   = (const float*)d_in[12];
    const float* gbhh   = (const float*)d_in[13];
    const float* lwih   = (const float*)d_in[14];
    const float* lwhh   = (const float*)d_in[15];
    const float* lbih   = (const float*)d_in[16];
    const float* lbhh   = (const float*)d_in[17];

    float* qstar = (float*)d_out;                 // [256*128]
    float* h     = (float*)d_out + NGB * 128;     // [N*64] == feat_map

    float* ws     = (float*)d_ws;
    float* W      = ws;                         // 4096
    float* agg    = ws + 4096;                  // N*64
    float* deg    = agg + NN * 64;              // N
    int*   cnt    = (int*)(deg + NN);           // 256
    int*   starts = cnt + 256;                  // 256
    float* hl     = (float*)(starts + 256);     // 256*64
    float* cl     = hl + NGB * 64;              // 256*64
    float* wihT   = cl + NGB * 64;              // 128*256
    float* whhT   = wihT + 128 * 256;           // 64*256
    float* e      = whhT + 64 * 256;            // N

    hipMemsetAsync(deg, 0, NN * sizeof(float), stream);
    hipMemsetAsync(cnt, 0, 256 * sizeof(int), stream);
    hipMemsetAsync(hl, 0, 2 * NGB * 64 * sizeof(float), stream);   // hl + cl
    hipMemsetAsync(qstar, 0, NGB * 128 * sizeof(float), stream);
    hipMemsetAsync(agg, 0, NN * 64 * sizeof(float), stream);       // once; k_update re-zeroes

    k_precompute_W<<<16, 256, 0, stream>>>(nn1_w, nn1_b, nn2_w, nn2_b, W);
    k_transpose_lstm<<<128, 256, 0, stream>>>(lwih, lwhh, wihT, whhT);
    k_deg_cnt<<<(NE + 255) / 256, 256, 0, stream>>>(ei, batch, deg, cnt);
    k_scan<<<1, 256, 0, stream>>>(cnt, starts);
    k_lin0<<<(NN + 3) / 4, 256, 0, stream>>>(x, lin0_w, lin0_b, h);

    for (int it = 0; it < 3; ++it) {
        k_scatter<<<(NE * 64 + 255) / 256, 256, 0, stream>>>(ei, h, agg);
        k_update<<<512, 1024, 0, stream>>>(agg, deg, W, conv_b, gwih, gwhh, gbih, gbhh, h, agg);
    }
    for (int st = 0; st < 3; ++st) {
        k_lstm<<<NGB, 64, 0, stream>>>(qstar, wihT, whhT, lbih, lbhh, hl, cl);
        k_dot<<<(NN * 64 + 255) / 256, 256, 0, stream>>>(h, hl, batch, e);
        k_attn2<<<NGB, 256, 0, stream>>>(h, hl, e, starts, cnt, qstar);
    }
}

// Round 6
// 669.124 us; speedup vs baseline: 1.6340x; 1.0548x over previous
//
#include <hip/hip_runtime.h>
#include <math.h>

#define NN 50000
#define NE 60000
#define FIN 32
#define DIM 64
#define NGB 256   // graphs in batch

__device__ __forceinline__ float rl(float v, int lane) {
    return __int_as_float(__builtin_amdgcn_readlane(__float_as_int(v), lane));
}
__device__ __forceinline__ float sigm(float x) { return 1.f / (1.f + expf(-x)); }

// pack two f32 as bf16 (RTN) into one u32: a -> low16, b -> high16
__device__ __forceinline__ unsigned int pk2(float a, float b) {
    unsigned int ua = __float_as_uint(a);
    unsigned int ub = __float_as_uint(b);
    ua = (ua + 0x7FFFu + ((ua >> 16) & 1u)) >> 16;
    ub = (ub + 0x7FFFu + ((ub >> 16) & 1u)) & 0xFFFF0000u;
    return ua | ub;
}
__device__ __forceinline__ float lo16(unsigned int w) { return __uint_as_float(w << 16); }
__device__ __forceinline__ float hi16(unsigned int w) { return __uint_as_float(w & 0xFFFF0000u); }

// ---------------- precompute: W[i*64+o] = (relu(nn1_w + nn1_b) @ nn2_w^T + nn2_b)
__global__ void k_precompute_W(const float* __restrict__ nn1_w, const float* __restrict__ nn1_b,
                               const float* __restrict__ nn2_w, const float* __restrict__ nn2_b,
                               float* __restrict__ W) {
    __shared__ float t[64];
    int tid = threadIdx.x;
    if (tid < 64) t[tid] = fmaxf(nn1_w[tid] + nn1_b[tid], 0.f);
    __syncthreads();
    int k = blockIdx.x * blockDim.x + tid;   // 0..4095
    float acc = nn2_b[k];
    #pragma unroll
    for (int j = 0; j < 64; ++j) acc += t[j] * nn2_w[k * 64 + j];
    W[k] = acc;
}

// ---------------- pre-pack GRU weights in the exact LDS layout (straight-copy staging)
// Gwp[(g*64+i)*64+l] = pk2(wih[(g*64+l)*64+i], whh[(g*64+l)*64+i])
__global__ void k_pack_gru(const float* __restrict__ wih, const float* __restrict__ whh,
                           unsigned int* __restrict__ Gwp) {
    int q = blockIdx.x * 256 + threadIdx.x;   // 48*256 = 12288
    int l = q & 63, i = (q >> 6) & 63, g = q >> 12;
    int row = (g * 64 + l) * 64 + i;
    Gwp[q] = pk2(wih[row], whh[row]);
}

// ---------------- transpose LSTM weights for coalesced gate dots
__global__ void k_transpose_lstm(const float* __restrict__ wih, const float* __restrict__ whh,
                                 float* __restrict__ wihT, float* __restrict__ whhT) {
    int p = blockIdx.x * 256 + threadIdx.x;
    if (p < 256 * 128) { int o = p >> 7, k = p & 127; wihT[k * 256 + o] = wih[p]; }
    if (p < 256 * 64)  { int o = p >> 6, k = p & 63;  whhT[k * 256 + o] = whh[p]; }
}

// ---------------- degree (over dst) + per-graph node counts
__global__ void k_deg_cnt(const int* __restrict__ ei, const int* __restrict__ batch,
                          float* __restrict__ deg, int* __restrict__ cnt) {
    int i = blockIdx.x * 256 + threadIdx.x;
    if (i < NE) atomicAdd(&deg[ei[NE + i]], 1.0f);
    if (i < NN) atomicAdd(&cnt[batch[i]], 1);
}

// ---------------- exclusive prefix scan of cnt[256] -> starts[256]
__global__ void k_scan(const int* __restrict__ cnt, int* __restrict__ starts) {
    __shared__ int sc[256];
    int t = threadIdx.x;
    int c = cnt[t];
    sc[t] = c;
    __syncthreads();
    for (int off = 1; off < 256; off <<= 1) {
        int v = (t >= off) ? sc[t - off] : 0;
        __syncthreads();
        sc[t] += v;
        __syncthreads();
    }
    starts[t] = sc[t] - c;
}

// ---------------- lin0: h = relu(x @ lin0_w^T + b), 64 lanes per node
__global__ void k_lin0(const float* __restrict__ x, const float* __restrict__ w,
                       const float* __restrict__ b, float* __restrict__ h) {
    __shared__ float wT[FIN * 64];   // wT[k*64+o] = w[o*32+k]
    int tid = threadIdx.x;
    for (int p = tid; p < FIN * 64; p += 256) {
        int o = p >> 5, k = p & 31;
        wT[k * 64 + o] = w[p];
    }
    __syncthreads();
    int l = tid & 63;
    int n = blockIdx.x * 4 + (tid >> 6);
    if (n >= NN) return;
    float xv = x[n * FIN + (l & 31)];
    float acc = b[l];
    #pragma unroll
    for (int k = 0; k < FIN; ++k) {
        float xk = rl(xv, k);
        acc += xk * wT[k * 64 + l];
    }
    h[n * 64 + l] = fmaxf(acc, 0.f);
}

// ---------------- scatter: agg[dst] += h[src]  (64 lanes per edge)
__global__ void k_scatter(const int* __restrict__ ei, const float* __restrict__ h,
                          float* __restrict__ agg) {
    int gid = blockIdx.x * 256 + threadIdx.x;
    int e = gid >> 6, l = gid & 63;
    if (e >= NE) return;
    int s = ei[e], d = ei[NE + e];
    atomicAdd(&agg[d * 64 + l], h[s * 64 + l]);
}

// ---------------- fused conv(W matvec)+GRU node update. static LDS = 64 KB.
// Round-3-proven arithmetic (f32 activations, bf16 weights unpacked to f32).
// Staging is a straight copy of pre-packed weights (conflict-free).
// Re-zeroes agg after reading (each n visited exactly once).
__global__ void __launch_bounds__(1024) k_update(
    const float* __restrict__ agg, const float* __restrict__ deg, const float* __restrict__ W,
    const unsigned int* __restrict__ Gwp, const float* __restrict__ conv_b,
    const float* __restrict__ bih, const float* __restrict__ bhh, float* __restrict__ h,
    float* __restrict__ aggz) {
    __shared__ float Wl[4096];              // 16 KB f32: Wl[j*64+l] = W[j*64+l]
    __shared__ unsigned int gw[12288];      // 48 KB bf16x2: gw[(g*64+i)*64+l]
    int tid = threadIdx.x;
    for (int p = tid; p < 4096; p += 1024) Wl[p] = W[p];
    for (int p = tid; p < 12288; p += 1024) gw[p] = Gwp[p];
    __syncthreads();
    int l = tid & 63;
    int wave = blockIdx.x * (blockDim.x >> 6) + (tid >> 6);
    int nwaves = gridDim.x * (blockDim.x >> 6);
    float cb = conv_b[l];
    float bi0 = bih[l], bi1 = bih[64 + l], bi2 = bih[128 + l];
    float bh0 = bhh[l], bh1 = bhh[64 + l], bh2 = bhh[128 + l];

    for (int t0 = wave * 4; t0 < NN; t0 += nwaves * 4) {   // NN % 4 == 0, no tail
        float aggv[4], hv[4];
        #pragma unroll
        for (int r = 0; r < 4; ++r) {
            int n = t0 + r;
            float d = deg[n];
            float inv = d > 0.f ? 1.f / d : 0.f;
            aggv[r] = agg[n * 64 + l] * inv;
            aggz[n * 64 + l] = 0.f;     // pre-zero for next scatter round
            hv[r]   = h[n * 64 + l];
        }
        // stage A: m = relu(aggv @ W + conv_b)   (f32)
        float mv[4] = {0.f, 0.f, 0.f, 0.f};
        #pragma unroll 8
        for (int j = 0; j < 64; ++j) {
            float wj = Wl[j * 64 + l];
            #pragma unroll
            for (int r = 0; r < 4; ++r) mv[r] += rl(aggv[r], j) * wj;
        }
        #pragma unroll
        for (int r = 0; r < 4; ++r) mv[r] = fmaxf(mv[r] + cb, 0.f);
        // stage B: gi = m @ Wih^T, gh = h @ Whh^T  (bf16 weights, f32 math)
        float ai[4][3], ah[4][3];
        #pragma unroll
        for (int r = 0; r < 4; ++r)
            #pragma unroll
            for (int g = 0; g < 3; ++g) { ai[r][g] = 0.f; ah[r][g] = 0.f; }
        #pragma unroll 4
        for (int i = 0; i < 64; ++i) {
            float sm[4], sh[4];
            #pragma unroll
            for (int r = 0; r < 4; ++r) { sm[r] = rl(mv[r], i); sh[r] = rl(hv[r], i); }
            #pragma unroll
            for (int g = 0; g < 3; ++g) {
                unsigned int w = gw[(g * 64 + i) * 64 + l];
                float wi = lo16(w), wh = hi16(w);
                #pragma unroll
                for (int r = 0; r < 4; ++r) { ai[r][g] += sm[r] * wi; ah[r][g] += sh[r] * wh; }
            }
        }
        #pragma unroll
        for (int r = 0; r < 4; ++r) {
            int n = t0 + r;
            float rg = sigm(ai[r][0] + bi0 + ah[r][0] + bh0);
            float zg = sigm(ai[r][1] + bi1 + ah[r][1] + bh1);
            float ng = tanhf(ai[r][2] + bi2 + rg * (ah[r][2] + bh2));
            h[n * 64 + l] = (1.f - zg) * ng + zg * hv[r];
        }
    }
}

// ---------------- fused Set2Set step: LSTM + segment softmax + weighted sum.
// One block (4 waves) per graph. e kept in LDS (counts ~195 << 768).
__global__ void k_s2s(const float* __restrict__ h, const int* __restrict__ starts,
                      const int* __restrict__ cnt, const float* __restrict__ wihT,
                      const float* __restrict__ whhT, const float* __restrict__ bih,
                      const float* __restrict__ bhh, float* __restrict__ hl,
                      float* __restrict__ cl, float* __restrict__ qstar, int first) {
    __shared__ float ga[256];
    __shared__ float hlv[64];
    __shared__ float els[768];
    __shared__ float red[8];
    __shared__ float bc[2];
    __shared__ float accw[4][64];
    int b = blockIdx.x, tid = threadIdx.x, w = tid >> 6, l = tid & 63;

    // ---- LSTM cell
    if (first) {
        if (tid < 64) {   // q_star = 0, hl = 0, cl = 0 -> gates are biases only
            float ig = sigm(bih[tid] + bhh[tid]);
            float gg = tanhf(bih[128 + tid] + bhh[128 + tid]);
            float og = sigm(bih[192 + tid] + bhh[192 + tid]);
            float c = ig * gg;                                // cl = 0
            cl[b * 64 + tid] = c;
            float hh = og * tanhf(c);
            hl[b * 64 + tid] = hh;
            hlv[tid] = hh;
        }
    } else {
        const float* qs = qstar + b * 128;
        const float* hb = hl + b * 64;
        float a = bih[tid] + bhh[tid];
        for (int k = 0; k < 128; ++k) a += qs[k] * wihT[k * 256 + tid];
        for (int k = 0; k < 64; ++k)  a += hb[k] * whhT[k * 256 + tid];
        ga[tid] = a;
        __syncthreads();
        if (tid < 64) {
            float c = sigm(ga[64 + tid]) * cl[b * 64 + tid] + sigm(ga[tid]) * tanhf(ga[128 + tid]);
            cl[b * 64 + tid] = c;
            float hh = sigm(ga[192 + tid]) * tanhf(c);
            hl[b * 64 + tid] = hh;
            hlv[tid] = hh;
        }
    }
    __syncthreads();

    int s = starts[b], c = cnt[b];
    int cc = c < 768 ? c : 768;
    float hld = hlv[l];
    // ---- phase A: e[i] = dot(h[s+i], hl); wave-striped; track max
    float mx = -1e30f;
    for (int i = w; i < c; i += 4) {
        float v = h[(s + i) * 64 + l] * hld;
        #pragma unroll
        for (int off = 32; off; off >>= 1) v += __shfl_xor(v, off, 64);
        if (l == 0 && i < 768) els[i] = v;
        mx = fmaxf(mx, v);
    }
    if (l == 0) red[w] = mx;
    __syncthreads();
    if (tid == 0) bc[0] = fmaxf(fmaxf(red[0], red[1]), fmaxf(red[2], red[3]));
    __syncthreads();
    float m = bc[0];
    // ---- phase B: a[i] = exp(e[i]-m); sum
    float ss = 0.f;
    for (int i = tid; i < cc; i += 256) {
        float a = expf(els[i] - m);
        els[i] = a;
        ss += a;
    }
    #pragma unroll
    for (int off = 32; off; off >>= 1) ss += __shfl_xor(ss, off, 64);
    if (l == 0) red[4 + w] = ss;
    __syncthreads();
    if (tid == 0) bc[1] = red[4] + red[5] + red[6] + red[7];
    __syncthreads();
    float asum = bc[1];
    // ---- phase C: r_vec = sum a[i] * h[s+i]
    float racc = 0.f;
    for (int i = w; i < cc; i += 4) racc += els[i] * h[(s + i) * 64 + l];
    accw[w][l] = racc;
    __syncthreads();
    if (w == 0) {
        float tot = accw[0][l] + accw[1][l] + accw[2][l] + accw[3][l];
        qstar[b * 128 + l] = hld;
        qstar[b * 128 + 64 + l] = tot / (asum + 1e-16f);
    }
}

extern "C" void kernel_launch(void* const* d_in, const int* in_sizes, int n_in,
                              void* d_out, int out_size, void* d_ws, size_t ws_size,
                              hipStream_t stream) {
    const float* x      = (const float*)d_in[0];
    const int*   ei     = (const int*)  d_in[1];
    const int*   batch  = (const int*)  d_in[2];
    const float* lin0_w = (const float*)d_in[3];
    const float* lin0_b = (const float*)d_in[4];
    const float* nn1_w  = (const float*)d_in[5];
    const float* nn1_b  = (const float*)d_in[6];
    const float* nn2_w  = (const float*)d_in[7];
    const float* nn2_b  = (const float*)d_in[8];
    const float* conv_b = (const float*)d_in[9];
    const float* gwih   = (const float*)d_in[10];
    const float* gwhh   = (const float*)d_in[11];
    const float* gbih   = (const float*)d_in[12];
    const float* gbhh   = (const float*)d_in[13];
    const float* lwih   = (const float*)d_in[14];
    const float* lwhh   = (const float*)d_in[15];
    const float* lbih   = (const float*)d_in[16];
    const float* lbhh   = (const float*)d_in[17];

    float* qstar = (float*)d_out;                 // [256*128]
    float* h     = (float*)d_out + NGB * 128;     // [N*64] == feat_map

    float* ws     = (float*)d_ws;
    float* W      = ws;                         // 4096
    float* agg    = ws + 4096;                  // N*64
    float* deg    = agg + NN * 64;              // N
    int*   cnt    = (int*)(deg + NN);           // 256
    int*   starts = cnt + 256;                  // 256
    float* hl     = (float*)(starts + 256);     // 256*64
    float* cl     = hl + NGB * 64;              // 256*64
    float* wihT   = cl + NGB * 64;              // 128*256
    float* whhT   = wihT + 128 * 256;           // 64*256
    unsigned int* Gwp = (unsigned int*)(whhT + 64 * 256);  // 12288

    hipMemsetAsync(deg, 0, NN * sizeof(float), stream);
    hipMemsetAsync(cnt, 0, 256 * sizeof(int), stream);
    hipMemsetAsync(agg, 0, NN * 64 * sizeof(float), stream);   // once; k_update re-zeroes

    k_precompute_W<<<16, 256, 0, stream>>>(nn1_w, nn1_b, nn2_w, nn2_b, W);
    k_pack_gru<<<48, 256, 0, stream>>>(gwih, gwhh, Gwp);
    k_transpose_lstm<<<128, 256, 0, stream>>>(lwih, lwhh, wihT, whhT);
    k_deg_cnt<<<(NE + 255) / 256, 256, 0, stream>>>(ei, batch, deg, cnt);
    k_scan<<<1, 256, 0, stream>>>(cnt, starts);
    k_lin0<<<(NN + 3) / 4, 256, 0, stream>>>(x, lin0_w, lin0_b, h);

    for (int it = 0; it < 3; ++it) {
        k_scatter<<<(NE * 64 + 255) / 256, 256, 0, stream>>>(ei, h, agg);
        k_update<<<512, 1024, 0, stream>>>(agg, deg, W, Gwp, conv_b,
                                           gbih, gbhh, h, agg);
    }
    for (int st = 0; st < 3; ++st) {
        k_s2s<<<NGB, 256, 0, stream>>>(h, starts, cnt, wihT, whhT, lbih, lbhh,
                                       hl, cl, qstar, st == 0 ? 1 : 0);
    }
}

// Round 7
// 436.627 us; speedup vs baseline: 2.5041x; 1.5325x over previous
//
#include <hip/hip_runtime.h>
#include <math.h>

#define NN 50000
#define NE 60000
#define FIN 32
#define DIM 64
#define NGB 256   // graphs in batch

typedef short s8v __attribute__((ext_vector_type(8)));
typedef float f4v __attribute__((ext_vector_type(4)));

__device__ __forceinline__ float rl(float v, int lane) {
    return __int_as_float(__builtin_amdgcn_readlane(__float_as_int(v), lane));
}
__device__ __forceinline__ float sigm(float x) { return 1.f / (1.f + expf(-x)); }

// pack two f32 as bf16 (RTN-even) into one u32: a -> low16, b -> high16
__device__ __forceinline__ unsigned int pk2(float a, float b) {
    unsigned int ua = __float_as_uint(a);
    unsigned int ub = __float_as_uint(b);
    ua = (ua + 0x7FFFu + ((ua >> 16) & 1u)) >> 16;
    ub = (ub + 0x7FFFu + ((ub >> 16) & 1u)) & 0xFFFF0000u;
    return ua | ub;
}
__device__ __forceinline__ unsigned short pk1(float a) {
    unsigned int ua = __float_as_uint(a);
    return (unsigned short)((ua + 0x7FFFu + ((ua >> 16) & 1u)) >> 16);
}
__device__ __forceinline__ s8v as_s8(uint4 u) {
    union { uint4 a; s8v b; } c; c.a = u; return c.b;
}

// ---------------- precompute: W[i*64+o] = (relu(nn1_w + nn1_b) @ nn2_w^T + nn2_b)
__global__ void k_precompute_W(const float* __restrict__ nn1_w, const float* __restrict__ nn1_b,
                               const float* __restrict__ nn2_w, const float* __restrict__ nn2_b,
                               float* __restrict__ W) {
    __shared__ float t[64];
    int tid = threadIdx.x;
    if (tid < 64) t[tid] = fmaxf(nn1_w[tid] + nn1_b[tid], 0.f);
    __syncthreads();
    int k = blockIdx.x * blockDim.x + tid;   // 0..4095
    float acc = nn2_b[k];
    #pragma unroll
    for (int j = 0; j < 64; ++j) acc += t[j] * nn2_w[k * 64 + j];
    W[k] = acc;
}

// ---------------- pack weights into MFMA B-fragment layouts (bf16, XOR-swizzled)
// Regions in P (u32 index):
//   [0,2048)      WpA : W as B[k=0..63][col=0..63], col stride 128 B
//   [2048,10240)  B01 : [wih_r|z ; whh_r|z] as B[k=0..127][col=0..127], col stride 256 B
//   [10240,12288) BnI : wih_n as B[k][col], col stride 128 B
//   [12288,14336) BnH : whh_n as B[k][col], col stride 128 B
// Within a col's row, 16B slot at byte kk*2 stored at (kk*2) ^ ((col&7)<<4).
__global__ void k_pack_mfma(const float* __restrict__ W, const float* __restrict__ wih,
                            const float* __restrict__ whh, const float* __restrict__ bih,
                            const float* __restrict__ bhh, unsigned int* __restrict__ P,
                            float* __restrict__ brz) {
    int q = blockIdx.x * 256 + threadIdx.x;   // 56*256 = 14336
    if (q < 128) brz[q] = bih[q] + bhh[q];    // summed r,z biases
    if (q < 2048) {                           // WpA
        int byte = q * 4, col = byte >> 7, rem = byte & 127;
        int lin = rem ^ ((col & 7) << 4);
        int k0 = (lin >> 4) * 8 + ((lin >> 2) & 3) * 2;
        P[q] = pk2(W[k0 * 64 + col], W[(k0 + 1) * 64 + col]);
    } else if (q < 10240) {                   // B01 (K=128)
        int w = q - 2048, byte = w * 4, col = byte >> 8, rem = byte & 255;
        int lin = rem ^ ((col & 7) << 4);
        int k0 = (lin >> 4) * 8 + ((lin >> 2) & 3) * 2;
        int g = col >> 6, o = col & 63;
        int rowbase = (g * 64 + o) * 64;
        const float* src = (k0 >= 64) ? whh : wih;
        int kk = (k0 >= 64) ? k0 - 64 : k0;
        P[q] = pk2(src[rowbase + kk], src[rowbase + kk + 1]);
    } else if (q < 12288) {                   // BnI
        int w = q - 10240, byte = w * 4, col = byte >> 7, rem = byte & 127;
        int lin = rem ^ ((col & 7) << 4);
        int k0 = (lin >> 4) * 8 + ((lin >> 2) & 3) * 2;
        P[q] = pk2(wih[(128 + col) * 64 + k0], wih[(128 + col) * 64 + k0 + 1]);
    } else {                                  // BnH
        int w = q - 12288, byte = w * 4, col = byte >> 7, rem = byte & 127;
        int lin = rem ^ ((col & 7) << 4);
        int k0 = (lin >> 4) * 8 + ((lin >> 2) & 3) * 2;
        P[q] = pk2(whh[(128 + col) * 64 + k0], whh[(128 + col) * 64 + k0 + 1]);
    }
}

// ---------------- transpose LSTM weights for coalesced gate dots
__global__ void k_transpose_lstm(const float* __restrict__ wih, const float* __restrict__ whh,
                                 float* __restrict__ wihT, float* __restrict__ whhT) {
    int p = blockIdx.x * 256 + threadIdx.x;
    if (p < 256 * 128) { int o = p >> 7, k = p & 127; wihT[k * 256 + o] = wih[p]; }
    if (p < 256 * 64)  { int o = p >> 6, k = p & 63;  whhT[k * 256 + o] = whh[p]; }
}

// ---------------- degree (over dst) + per-graph node counts
__global__ void k_deg_cnt(const int* __restrict__ ei, const int* __restrict__ batch,
                          float* __restrict__ deg, int* __restrict__ cnt) {
    int i = blockIdx.x * 256 + threadIdx.x;
    if (i < NE) atomicAdd(&deg[ei[NE + i]], 1.0f);
    if (i < NN) atomicAdd(&cnt[batch[i]], 1);
}

// ---------------- exclusive prefix scan of cnt[256] -> starts[256]
__global__ void k_scan(const int* __restrict__ cnt, int* __restrict__ starts) {
    __shared__ int sc[256];
    int t = threadIdx.x;
    int c = cnt[t];
    sc[t] = c;
    __syncthreads();
    for (int off = 1; off < 256; off <<= 1) {
        int v = (t >= off) ? sc[t - off] : 0;
        __syncthreads();
        sc[t] += v;
        __syncthreads();
    }
    starts[t] = sc[t] - c;
}

// ---------------- lin0: h = relu(x @ lin0_w^T + b), 64 lanes per node
__global__ void k_lin0(const float* __restrict__ x, const float* __restrict__ w,
                       const float* __restrict__ b, float* __restrict__ h) {
    __shared__ float wT[FIN * 64];   // wT[k*64+o] = w[o*32+k]
    int tid = threadIdx.x;
    for (int p = tid; p < FIN * 64; p += 256) {
        int o = p >> 5, k = p & 31;
        wT[k * 64 + o] = w[p];
    }
    __syncthreads();
    int l = tid & 63;
    int n = blockIdx.x * 4 + (tid >> 6);
    if (n >= NN) return;
    float xv = x[n * FIN + (l & 31)];
    float acc = b[l];
    #pragma unroll
    for (int k = 0; k < FIN; ++k) {
        float xk = rl(xv, k);
        acc += xk * wT[k * 64 + l];
    }
    h[n * 64 + l] = fmaxf(acc, 0.f);
}

// ---------------- scatter: agg[dst] += h[src]  (64 lanes per edge)
__global__ void k_scatter(const int* __restrict__ ei, const float* __restrict__ h,
                          float* __restrict__ agg) {
    int gid = blockIdx.x * 256 + threadIdx.x;
    int e = gid >> 6, l = gid & 63;
    if (e >= NE) return;
    int s = ei[e], d = ei[NE + e];
    atomicAdd(&agg[d * 64 + l], h[s * 64 + l]);
}

// ---------------- MFMA conv(W)+GRU node update. Wave = 16 nodes, block = 4 waves.
// LDS: 56 KB pre-packed bf16 weights (straight copy) + 4 x 2 KB per-wave m-transpose.
// Re-zeroes agg after reading (each element exactly once).
__global__ void __launch_bounds__(256) k_update(
    const float* __restrict__ agg, const float* __restrict__ deg,
    const unsigned int* __restrict__ P, const float* __restrict__ conv_b,
    const float* __restrict__ brz, const float* __restrict__ bih, const float* __restrict__ bhh,
    float* __restrict__ h, float* __restrict__ aggz) {
    __shared__ unsigned int L[16384];   // 64 KB
    int tid = threadIdx.x;
    #pragma unroll
    for (int p = 0; p < 14336; p += 256) L[p + tid] = P[p + tid];
    __syncthreads();

    int l = tid & 63;
    int w = tid >> 6;
    int nb = (blockIdx.x * 4 + w) * 16;
    if (nb >= NN) return;               // idle waves in last block (after barrier)
    int row = l & 15, kq = l >> 4;      // A/B frag: row/col = lane&15, k-chunk = lane>>4
    int node = nb + row;

    float dv = deg[node];
    float inv = dv > 0.f ? 1.f / dv : 0.f;

    // ---- A-frags of agg_mean (bf16), zero agg behind us
    uint4 aA[2];
    #pragma unroll
    for (int kt = 0; kt < 2; ++kt) {
        const float4* src = (const float4*)(agg + node * 64 + kt * 32 + kq * 8);
        float4 x0 = src[0], x1 = src[1];
        float4 z4 = {0.f, 0.f, 0.f, 0.f};
        ((float4*)(aggz + node * 64 + kt * 32 + kq * 8))[0] = z4;
        ((float4*)(aggz + node * 64 + kt * 32 + kq * 8))[1] = z4;
        aA[kt].x = pk2(x0.x * inv, x0.y * inv);
        aA[kt].y = pk2(x0.z * inv, x0.w * inv);
        aA[kt].z = pk2(x1.x * inv, x1.y * inv);
        aA[kt].w = pk2(x1.z * inv, x1.w * inv);
    }

    // ---- stage A: m = relu(aggmean @ W + conv_b)
    f4v mC[4];
    #pragma unroll
    for (int ct = 0; ct < 4; ++ct) {
        f4v acc = {0.f, 0.f, 0.f, 0.f};
        int col = ct * 16 + row;
        #pragma unroll
        for (int kt = 0; kt < 2; ++kt) {
            int boff = col * 128 + ((kt * 64 + kq * 16) ^ ((col & 7) << 4));
            uint4 b = *(const uint4*)((const char*)L + boff);
            acc = __builtin_amdgcn_mfma_f32_16x16x32_bf16(as_s8(aA[kt]), as_s8(b), acc, 0, 0, 0);
        }
        mC[ct] = acc;
    }

    // ---- transpose m to A-frag layout via per-wave LDS region (swizzled)
    int mbase = 57344 + w * 2048;
    #pragma unroll
    for (int ct = 0; ct < 4; ++ct) {
        int ch = ct * 16 + row;
        float cb = conv_b[ch];
        #pragma unroll
        for (int r = 0; r < 4; ++r) {
            float mval = fmaxf(mC[ct][r] + cb, 0.f);
            int nrow = kq * 4 + r;
            int off = mbase + ((nrow * 128 + ch * 2) ^ ((nrow & 7) << 4));
            *(unsigned short*)((char*)L + off) = pk1(mval);
        }
    }
    // same-wave DS ordering: reads below see the writes above (no block barrier needed)
    uint4 mA[2], hA[2];
    #pragma unroll
    for (int kt = 0; kt < 2; ++kt) {
        int off = mbase + ((row * 128 + kt * 64 + kq * 16) ^ ((row & 7) << 4));
        mA[kt] = *(const uint4*)((const char*)L + off);
        const float4* hs = (const float4*)(h + node * 64 + kt * 32 + kq * 8);
        float4 y0 = hs[0], y1 = hs[1];
        hA[kt].x = pk2(y0.x, y0.y);
        hA[kt].y = pk2(y0.z, y0.w);
        hA[kt].z = pk2(y1.x, y1.y);
        hA[kt].w = pk2(y1.z, y1.w);
    }

    // ---- gates r,z: [m|h](16x128) @ B01(128x128)
    f4v g01[8];
    #pragma unroll
    for (int ct = 0; ct < 8; ++ct) {
        f4v acc = {0.f, 0.f, 0.f, 0.f};
        int col = ct * 16 + row;
        #pragma unroll
        for (int kt = 0; kt < 4; ++kt) {
            uint4 a = (kt < 2) ? mA[kt] : hA[kt - 2];
            int boff = 8192 + col * 256 + ((kt * 64 + kq * 16) ^ ((col & 7) << 4));
            uint4 b = *(const uint4*)((const char*)L + boff);
            acc = __builtin_amdgcn_mfma_f32_16x16x32_bf16(as_s8(a), as_s8(b), acc, 0, 0, 0);
        }
        g01[ct] = acc;
    }
    // ---- i_n = m @ wih_n^T ; h_n = h @ whh_n^T
    f4v gin[4], ghn[4];
    #pragma unroll
    for (int ct = 0; ct < 4; ++ct) {
        f4v ai = {0.f, 0.f, 0.f, 0.f}, ah = {0.f, 0.f, 0.f, 0.f};
        int col = ct * 16 + row;
        #pragma unroll
        for (int kt = 0; kt < 2; ++kt) {
            int swz = (kt * 64 + kq * 16) ^ ((col & 7) << 4);
            uint4 bi = *(const uint4*)((const char*)L + 40960 + col * 128 + swz);
            uint4 bh = *(const uint4*)((const char*)L + 49152 + col * 128 + swz);
            ai = __builtin_amdgcn_mfma_f32_16x16x32_bf16(as_s8(mA[kt]), as_s8(bi), ai, 0, 0, 0);
            ah = __builtin_amdgcn_mfma_f32_16x16x32_bf16(as_s8(hA[kt]), as_s8(bh), ah, 0, 0, 0);
        }
        gin[ct] = ai; ghn[ct] = ah;
    }

    // ---- epilogue: GRU cell in C-frag layout (col=lane&15, row=(lane>>4)*4+r)
    #pragma unroll
    for (int ct = 0; ct < 4; ++ct) {
        int ch = ct * 16 + row;
        float br = brz[ch], bz = brz[64 + ch];
        float bin = bih[128 + ch], bhn = bhh[128 + ch];
        #pragma unroll
        for (int r = 0; r < 4; ++r) {
            int n2 = nb + kq * 4 + r;
            float rg = sigm(g01[ct][r] + br);
            float zg = sigm(g01[4 + ct][r] + bz);
            float ng = tanhf(gin[ct][r] + bin + rg * (ghn[ct][r] + bhn));
            float hold = h[n2 * 64 + ch];
            h[n2 * 64 + ch] = (1.f - zg) * ng + zg * hold;
        }
    }
}

// ---------------- fused Set2Set step: LSTM + segment softmax + weighted sum.
__global__ void k_s2s(const float* __restrict__ h, const int* __restrict__ starts,
                      const int* __restrict__ cnt, const float* __restrict__ wihT,
                      const float* __restrict__ whhT, const float* __restrict__ bih,
                      const float* __restrict__ bhh, float* __restrict__ hl,
                      float* __restrict__ cl, float* __restrict__ qstar, int first) {
    __shared__ float ga[256];
    __shared__ float hlv[64];
    __shared__ float els[768];
    __shared__ float red[8];
    __shared__ float bc[2];
    __shared__ float accw[4][64];
    int b = blockIdx.x, tid = threadIdx.x, w = tid >> 6, l = tid & 63;

    if (first) {
        if (tid < 64) {   // q_star = 0, hl = 0, cl = 0 -> gates are biases only
            float ig = sigm(bih[tid] + bhh[tid]);
            float gg = tanhf(bih[128 + tid] + bhh[128 + tid]);
            float og = sigm(bih[192 + tid] + bhh[192 + tid]);
            float c = ig * gg;
            cl[b * 64 + tid] = c;
            float hh = og * tanhf(c);
            hl[b * 64 + tid] = hh;
            hlv[tid] = hh;
        }
    } else {
        const float* qs = qstar + b * 128;
        const float* hb = hl + b * 64;
        float a = bih[tid] + bhh[tid];
        for (int k = 0; k < 128; ++k) a += qs[k] * wihT[k * 256 + tid];
        for (int k = 0; k < 64; ++k)  a += hb[k] * whhT[k * 256 + tid];
        ga[tid] = a;
        __syncthreads();
        if (tid < 64) {
            float c = sigm(ga[64 + tid]) * cl[b * 64 + tid] + sigm(ga[tid]) * tanhf(ga[128 + tid]);
            cl[b * 64 + tid] = c;
            float hh = sigm(ga[192 + tid]) * tanhf(c);
            hl[b * 64 + tid] = hh;
            hlv[tid] = hh;
        }
    }
    __syncthreads();

    int s = starts[b], c = cnt[b];
    int cc = c < 768 ? c : 768;
    float hld = hlv[l];
    float mx = -1e30f;
    for (int i = w; i < c; i += 4) {
        float v = h[(s + i) * 64 + l] * hld;
        #pragma unroll
        for (int off = 32; off; off >>= 1) v += __shfl_xor(v, off, 64);
        if (l == 0 && i < 768) els[i] = v;
        mx = fmaxf(mx, v);
    }
    if (l == 0) red[w] = mx;
    __syncthreads();
    if (tid == 0) bc[0] = fmaxf(fmaxf(red[0], red[1]), fmaxf(red[2], red[3]));
    __syncthreads();
    float m = bc[0];
    float ss = 0.f;
    for (int i = tid; i < cc; i += 256) {
        float a = expf(els[i] - m);
        els[i] = a;
        ss += a;
    }
    #pragma unroll
    for (int off = 32; off; off >>= 1) ss += __shfl_xor(ss, off, 64);
    if (l == 0) red[4 + w] = ss;
    __syncthreads();
    if (tid == 0) bc[1] = red[4] + red[5] + red[6] + red[7];
    __syncthreads();
    float asum = bc[1];
    float racc = 0.f;
    for (int i = w; i < cc; i += 4) racc += els[i] * h[(s + i) * 64 + l];
    accw[w][l] = racc;
    __syncthreads();
    if (w == 0) {
        float tot = accw[0][l] + accw[1][l] + accw[2][l] + accw[3][l];
        qstar[b * 128 + l] = hld;
        qstar[b * 128 + 64 + l] = tot / (asum + 1e-16f);
    }
}

extern "C" void kernel_launch(void* const* d_in, const int* in_sizes, int n_in,
                              void* d_out, int out_size, void* d_ws, size_t ws_size,
                              hipStream_t stream) {
    const float* x      = (const float*)d_in[0];
    const int*   ei     = (const int*)  d_in[1];
    const int*   batch  = (const int*)  d_in[2];
    const float* lin0_w = (const float*)d_in[3];
    const float* lin0_b = (const float*)d_in[4];
    const float* nn1_w  = (const float*)d_in[5];
    const float* nn1_b  = (const float*)d_in[6];
    const float* nn2_w  = (const float*)d_in[7];
    const float* nn2_b  = (const float*)d_in[8];
    const float* conv_b = (const float*)d_in[9];
    const float* gwih   = (const float*)d_in[10];
    const float* gwhh   = (const float*)d_in[11];
    const float* gbih   = (const float*)d_in[12];
    const float* gbhh   = (const float*)d_in[13];
    const float* lwih   = (const float*)d_in[14];
    const float* lwhh   = (const float*)d_in[15];
    const float* lbih   = (const float*)d_in[16];
    const float* lbhh   = (const float*)d_in[17];

    float* qstar = (float*)d_out;                 // [256*128]
    float* h     = (float*)d_out + NGB * 128;     // [N*64] == feat_map

    float* ws     = (float*)d_ws;
    float* W      = ws;                         // 4096
    float* agg    = ws + 4096;                  // N*64
    float* deg    = agg + NN * 64;              // N
    int*   cnt    = (int*)(deg + NN);           // 256
    int*   starts = cnt + 256;                  // 256
    float* hl     = (float*)(starts + 256);     // 256*64
    float* cl     = hl + NGB * 64;              // 256*64
    float* wihT   = cl + NGB * 64;              // 128*256
    float* whhT   = wihT + 128 * 256;           // 64*256
    unsigned int* P = (unsigned int*)(whhT + 64 * 256);  // 14336
    float* brz    = (float*)(P + 14336);        // 128

    hipMemsetAsync(deg, 0, NN * sizeof(float), stream);
    hipMemsetAsync(cnt, 0, 256 * sizeof(int), stream);
    hipMemsetAsync(agg, 0, NN * 64 * sizeof(float), stream);   // once; k_update re-zeroes

    k_precompute_W<<<16, 256, 0, stream>>>(nn1_w, nn1_b, nn2_w, nn2_b, W);
    k_pack_mfma<<<56, 256, 0, stream>>>(W, gwih, gwhh, gbih, gbhh, P, brz);
    k_transpose_lstm<<<128, 256, 0, stream>>>(lwih, lwhh, wihT, whhT);
    k_deg_cnt<<<(NE + 255) / 256, 256, 0, stream>>>(ei, batch, deg, cnt);
    k_scan<<<1, 256, 0, stream>>>(cnt, starts);
    k_lin0<<<(NN + 3) / 4, 256, 0, stream>>>(x, lin0_w, lin0_b, h);

    for (int it = 0; it < 3; ++it) {
        k_scatter<<<(NE * 64 + 255) / 256, 256, 0, stream>>>(ei, h, agg);
        k_update<<<782, 256, 0, stream>>>(agg, deg, P, conv_b, brz, gbih, gbhh, h, agg);
    }
    for (int st = 0; st < 3; ++st) {
        k_s2s<<<NGB, 256, 0, stream>>>(h, starts, cnt, wihT, whhT, lbih, lbhh,
                                       hl, cl, qstar, st == 0 ? 1 : 0);
    }
}

// Round 8
// 380.361 us; speedup vs baseline: 2.8745x; 1.1479x over previous
//
#include <hip/hip_runtime.h>
#include <math.h>

#define NN 50000
#define NE 60000
#define FIN 32
#define DIM 64
#define NGB 256   // graphs in batch

typedef short s8v __attribute__((ext_vector_type(8)));
typedef float f4v __attribute__((ext_vector_type(4)));

__device__ __forceinline__ float rl(float v, int lane) {
    return __int_as_float(__builtin_amdgcn_readlane(__float_as_int(v), lane));
}
__device__ __forceinline__ float sigm(float x) { return 1.f / (1.f + expf(-x)); }

// pack two f32 as bf16 (RTN-even) into one u32: a -> low16, b -> high16
__device__ __forceinline__ unsigned int pk2(float a, float b) {
    unsigned int ua = __float_as_uint(a);
    unsigned int ub = __float_as_uint(b);
    ua = (ua + 0x7FFFu + ((ua >> 16) & 1u)) >> 16;
    ub = (ub + 0x7FFFu + ((ub >> 16) & 1u)) & 0xFFFF0000u;
    return ua | ub;
}
__device__ __forceinline__ unsigned short pk1(float a) {
    unsigned int ua = __float_as_uint(a);
    return (unsigned short)((ua + 0x7FFFu + ((ua >> 16) & 1u)) >> 16);
}
__device__ __forceinline__ s8v as_s8(uint4 u) {
    union { uint4 a; s8v b; } c; c.a = u; return c.b;
}

// ---------------- precompute: W[i*64+o] = (relu(nn1_w + nn1_b) @ nn2_w^T + nn2_b)
__global__ void k_precompute_W(const float* __restrict__ nn1_w, const float* __restrict__ nn1_b,
                               const float* __restrict__ nn2_w, const float* __restrict__ nn2_b,
                               float* __restrict__ W) {
    __shared__ float t[64];
    int tid = threadIdx.x;
    if (tid < 64) t[tid] = fmaxf(nn1_w[tid] + nn1_b[tid], 0.f);
    __syncthreads();
    int k = blockIdx.x * blockDim.x + tid;   // 0..4095
    float acc = nn2_b[k];
    #pragma unroll
    for (int j = 0; j < 64; ++j) acc += t[j] * nn2_w[k * 64 + j];
    W[k] = acc;
}

// ---------------- pack weights into MFMA B-fragment layouts (bf16, XOR-swizzled)
// Regions in P (u32 index):
//   [0,2048)      WpA : W as B[k=0..63][col=0..63], col stride 128 B
//   [2048,10240)  B01 : [wih_r|z ; whh_r|z] as B[k=0..127][col=0..127], col stride 256 B
//   [10240,12288) BnI : wih_n as B[k][col], col stride 128 B
//   [12288,14336) BnH : whh_n as B[k][col], col stride 128 B
// Within a col's row, 16B slot at byte kk*2 stored at (kk*2) ^ ((col&7)<<4).
__global__ void k_pack_mfma(const float* __restrict__ W, const float* __restrict__ wih,
                            const float* __restrict__ whh, const float* __restrict__ bih,
                            const float* __restrict__ bhh, unsigned int* __restrict__ P,
                            float* __restrict__ brz) {
    int q = blockIdx.x * 256 + threadIdx.x;   // 56*256 = 14336
    if (q < 128) brz[q] = bih[q] + bhh[q];    // summed r,z biases
    if (q < 2048) {                           // WpA
        int byte = q * 4, col = byte >> 7, rem = byte & 127;
        int lin = rem ^ ((col & 7) << 4);
        int k0 = (lin >> 4) * 8 + ((lin >> 2) & 3) * 2;
        P[q] = pk2(W[k0 * 64 + col], W[(k0 + 1) * 64 + col]);
    } else if (q < 10240) {                   // B01 (K=128)
        int w = q - 2048, byte = w * 4, col = byte >> 8, rem = byte & 255;
        int lin = rem ^ ((col & 7) << 4);
        int k0 = (lin >> 4) * 8 + ((lin >> 2) & 3) * 2;
        int g = col >> 6, o = col & 63;
        int rowbase = (g * 64 + o) * 64;
        const float* src = (k0 >= 64) ? whh : wih;
        int kk = (k0 >= 64) ? k0 - 64 : k0;
        P[q] = pk2(src[rowbase + kk], src[rowbase + kk + 1]);
    } else if (q < 12288) {                   // BnI
        int w = q - 10240, byte = w * 4, col = byte >> 7, rem = byte & 127;
        int lin = rem ^ ((col & 7) << 4);
        int k0 = (lin >> 4) * 8 + ((lin >> 2) & 3) * 2;
        P[q] = pk2(wih[(128 + col) * 64 + k0], wih[(128 + col) * 64 + k0 + 1]);
    } else {                                  // BnH
        int w = q - 12288, byte = w * 4, col = byte >> 7, rem = byte & 127;
        int lin = rem ^ ((col & 7) << 4);
        int k0 = (lin >> 4) * 8 + ((lin >> 2) & 3) * 2;
        P[q] = pk2(whh[(128 + col) * 64 + k0], whh[(128 + col) * 64 + k0 + 1]);
    }
}

// ---------------- transpose LSTM weights for coalesced gate dots
__global__ void k_transpose_lstm(const float* __restrict__ wih, const float* __restrict__ whh,
                                 float* __restrict__ wihT, float* __restrict__ whhT) {
    int p = blockIdx.x * 256 + threadIdx.x;
    if (p < 256 * 128) { int o = p >> 7, k = p & 127; wihT[k * 256 + o] = wih[p]; }
    if (p < 256 * 64)  { int o = p >> 6, k = p & 63;  whhT[k * 256 + o] = whh[p]; }
}

// ---------------- degree over dst (edge atomics only; low contention)
__global__ void k_deg(const int* __restrict__ ei, float* __restrict__ deg) {
    int i = blockIdx.x * 256 + threadIdx.x;
    if (i < NE) atomicAdd(&deg[ei[NE + i]], 1.0f);
}

// ---------------- per-graph starts/cnt via binary search on sorted batch (no atomics)
__global__ void k_bounds(const int* __restrict__ batch, int* __restrict__ starts,
                         int* __restrict__ cnt) {
    __shared__ int sLB[257];
    int b = threadIdx.x;   // 0..255
    int lo = 0, hi = NN;
    while (lo < hi) {      // lower_bound(batch, b)
        int mid = (lo + hi) >> 1;
        if (batch[mid] < b) lo = mid + 1; else hi = mid;
    }
    sLB[b] = lo;
    if (b == 0) sLB[256] = NN;
    __syncthreads();
    starts[b] = sLB[b];
    cnt[b] = sLB[b + 1] - sLB[b];
}

// ---------------- lin0: h = relu(x @ lin0_w^T + b), 64 lanes per node
__global__ void k_lin0(const float* __restrict__ x, const float* __restrict__ w,
                       const float* __restrict__ b, float* __restrict__ h) {
    __shared__ float wT[FIN * 64];   // wT[k*64+o] = w[o*32+k]
    int tid = threadIdx.x;
    for (int p = tid; p < FIN * 64; p += 256) {
        int o = p >> 5, k = p & 31;
        wT[k * 64 + o] = w[p];
    }
    __syncthreads();
    int l = tid & 63;
    int n = blockIdx.x * 4 + (tid >> 6);
    if (n >= NN) return;
    float xv = x[n * FIN + (l & 31)];
    float acc = b[l];
    #pragma unroll
    for (int k = 0; k < FIN; ++k) {
        float xk = rl(xv, k);
        acc += xk * wT[k * 64 + l];
    }
    h[n * 64 + l] = fmaxf(acc, 0.f);
}

// ---------------- scatter: agg[dst] += h[src]  (64 lanes per edge)
__global__ void k_scatter(const int* __restrict__ ei, const float* __restrict__ h,
                          float* __restrict__ agg) {
    int gid = blockIdx.x * 256 + threadIdx.x;
    int e = gid >> 6, l = gid & 63;
    if (e >= NE) return;
    int s = ei[e], d = ei[NE + e];
    atomicAdd(&agg[d * 64 + l], h[s * 64 + l]);
}

// ---------------- MFMA conv(W)+GRU node update. Wave = 16 nodes, block = 4 waves.
// LDS: 56 KB pre-packed bf16 weights (straight copy) + 4 x 2 KB per-wave m-transpose.
// Re-zeroes agg after reading (each element exactly once).
__global__ void __launch_bounds__(256) k_update(
    const float* __restrict__ agg, const float* __restrict__ deg,
    const unsigned int* __restrict__ P, const float* __restrict__ conv_b,
    const float* __restrict__ brz, const float* __restrict__ bih, const float* __restrict__ bhh,
    float* __restrict__ h, float* __restrict__ aggz) {
    __shared__ unsigned int L[16384];   // 64 KB
    int tid = threadIdx.x;
    #pragma unroll
    for (int p = 0; p < 14336; p += 256) L[p + tid] = P[p + tid];
    __syncthreads();

    int l = tid & 63;
    int w = tid >> 6;
    int nb = (blockIdx.x * 4 + w) * 16;
    if (nb >= NN) return;               // idle waves in last block (after barrier)
    int row = l & 15, kq = l >> 4;      // A/B frag: row/col = lane&15, k-chunk = lane>>4
    int node = nb + row;

    float dv = deg[node];
    float inv = dv > 0.f ? 1.f / dv : 0.f;

    // ---- A-frags of agg_mean (bf16), zero agg behind us
    uint4 aA[2];
    #pragma unroll
    for (int kt = 0; kt < 2; ++kt) {
        const float4* src = (const float4*)(agg + node * 64 + kt * 32 + kq * 8);
        float4 x0 = src[0], x1 = src[1];
        float4 z4 = {0.f, 0.f, 0.f, 0.f};
        ((float4*)(aggz + node * 64 + kt * 32 + kq * 8))[0] = z4;
        ((float4*)(aggz + node * 64 + kt * 32 + kq * 8))[1] = z4;
        aA[kt].x = pk2(x0.x * inv, x0.y * inv);
        aA[kt].y = pk2(x0.z * inv, x0.w * inv);
        aA[kt].z = pk2(x1.x * inv, x1.y * inv);
        aA[kt].w = pk2(x1.z * inv, x1.w * inv);
    }

    // ---- stage A: m = relu(aggmean @ W + conv_b)
    f4v mC[4];
    #pragma unroll
    for (int ct = 0; ct < 4; ++ct) {
        f4v acc = {0.f, 0.f, 0.f, 0.f};
        int col = ct * 16 + row;
        #pragma unroll
        for (int kt = 0; kt < 2; ++kt) {
            int boff = col * 128 + ((kt * 64 + kq * 16) ^ ((col & 7) << 4));
            uint4 b = *(const uint4*)((const char*)L + boff);
            acc = __builtin_amdgcn_mfma_f32_16x16x32_bf16(as_s8(aA[kt]), as_s8(b), acc, 0, 0, 0);
        }
        mC[ct] = acc;
    }

    // ---- transpose m to A-frag layout via per-wave LDS region (swizzled)
    int mbase = 57344 + w * 2048;
    #pragma unroll
    for (int ct = 0; ct < 4; ++ct) {
        int ch = ct * 16 + row;
        float cb = conv_b[ch];
        #pragma unroll
        for (int r = 0; r < 4; ++r) {
            float mval = fmaxf(mC[ct][r] + cb, 0.f);
            int nrow = kq * 4 + r;
            int off = mbase + ((nrow * 128 + ch * 2) ^ ((nrow & 7) << 4));
            *(unsigned short*)((char*)L + off) = pk1(mval);
        }
    }
    // same-wave DS ordering: reads below see the writes above (no block barrier needed)
    uint4 mA[2], hA[2];
    #pragma unroll
    for (int kt = 0; kt < 2; ++kt) {
        int off = mbase + ((row * 128 + kt * 64 + kq * 16) ^ ((row & 7) << 4));
        mA[kt] = *(const uint4*)((const char*)L + off);
        const float4* hs = (const float4*)(h + node * 64 + kt * 32 + kq * 8);
        float4 y0 = hs[0], y1 = hs[1];
        hA[kt].x = pk2(y0.x, y0.y);
        hA[kt].y = pk2(y0.z, y0.w);
        hA[kt].z = pk2(y1.x, y1.y);
        hA[kt].w = pk2(y1.z, y1.w);
    }

    // ---- gates r,z: [m|h](16x128) @ B01(128x128)
    f4v g01[8];
    #pragma unroll
    for (int ct = 0; ct < 8; ++ct) {
        f4v acc = {0.f, 0.f, 0.f, 0.f};
        int col = ct * 16 + row;
        #pragma unroll
        for (int kt = 0; kt < 4; ++kt) {
            uint4 a = (kt < 2) ? mA[kt] : hA[kt - 2];
            int boff = 8192 + col * 256 + ((kt * 64 + kq * 16) ^ ((col & 7) << 4));
            uint4 b = *(const uint4*)((const char*)L + boff);
            acc = __builtin_amdgcn_mfma_f32_16x16x32_bf16(as_s8(a), as_s8(b), acc, 0, 0, 0);
        }
        g01[ct] = acc;
    }
    // ---- i_n = m @ wih_n^T ; h_n = h @ whh_n^T
    f4v gin[4], ghn[4];
    #pragma unroll
    for (int ct = 0; ct < 4; ++ct) {
        f4v ai = {0.f, 0.f, 0.f, 0.f}, ah = {0.f, 0.f, 0.f, 0.f};
        int col = ct * 16 + row;
        #pragma unroll
        for (int kt = 0; kt < 2; ++kt) {
            int swz = (kt * 64 + kq * 16) ^ ((col & 7) << 4);
            uint4 bi = *(const uint4*)((const char*)L + 40960 + col * 128 + swz);
            uint4 bh = *(const uint4*)((const char*)L + 49152 + col * 128 + swz);
            ai = __builtin_amdgcn_mfma_f32_16x16x32_bf16(as_s8(mA[kt]), as_s8(bi), ai, 0, 0, 0);
            ah = __builtin_amdgcn_mfma_f32_16x16x32_bf16(as_s8(hA[kt]), as_s8(bh), ah, 0, 0, 0);
        }
        gin[ct] = ai; ghn[ct] = ah;
    }

    // ---- epilogue: GRU cell in C-frag layout (col=lane&15, row=(lane>>4)*4+r)
    #pragma unroll
    for (int ct = 0; ct < 4; ++ct) {
        int ch = ct * 16 + row;
        float br = brz[ch], bz = brz[64 + ch];
        float bin = bih[128 + ch], bhn = bhh[128 + ch];
        #pragma unroll
        for (int r = 0; r < 4; ++r) {
            int n2 = nb + kq * 4 + r;
            float rg = sigm(g01[ct][r] + br);
            float zg = sigm(g01[4 + ct][r] + bz);
            float ng = tanhf(gin[ct][r] + bin + rg * (ghn[ct][r] + bhn));
            float hold = h[n2 * 64 + ch];
            h[n2 * 64 + ch] = (1.f - zg) * ng + zg * hold;
        }
    }
}

// ---------------- fused Set2Set step: LSTM + segment softmax + weighted sum.
__global__ void k_s2s(const float* __restrict__ h, const int* __restrict__ starts,
                      const int* __restrict__ cnt, const float* __restrict__ wihT,
                      const float* __restrict__ whhT, const float* __restrict__ bih,
                      const float* __restrict__ bhh, float* __restrict__ hl,
                      float* __restrict__ cl, float* __restrict__ qstar, int first) {
    __shared__ float ga[256];
    __shared__ float hlv[64];
    __shared__ float els[768];
    __shared__ float red[8];
    __shared__ float bc[2];
    __shared__ float accw[4][64];
    int b = blockIdx.x, tid = threadIdx.x, w = tid >> 6, l = tid & 63;

    if (first) {
        if (tid < 64) {   // q_star = 0, hl = 0, cl = 0 -> gates are biases only
            float ig = sigm(bih[tid] + bhh[tid]);
            float gg = tanhf(bih[128 + tid] + bhh[128 + tid]);
            float og = sigm(bih[192 + tid] + bhh[192 + tid]);
            float c = ig * gg;
            cl[b * 64 + tid] = c;
            float hh = og * tanhf(c);
            hl[b * 64 + tid] = hh;
            hlv[tid] = hh;
        }
    } else {
        const float* qs = qstar + b * 128;
        const float* hb = hl + b * 64;
        float a = bih[tid] + bhh[tid];
        for (int k = 0; k < 128; ++k) a += qs[k] * wihT[k * 256 + tid];
        for (int k = 0; k < 64; ++k)  a += hb[k] * whhT[k * 256 + tid];
        ga[tid] = a;
        __syncthreads();
        if (tid < 64) {
            float c = sigm(ga[64 + tid]) * cl[b * 64 + tid] + sigm(ga[tid]) * tanhf(ga[128 + tid]);
            cl[b * 64 + tid] = c;
            float hh = sigm(ga[192 + tid]) * tanhf(c);
            hl[b * 64 + tid] = hh;
            hlv[tid] = hh;
        }
    }
    __syncthreads();

    int s = starts[b], c = cnt[b];
    int cc = c < 768 ? c : 768;
    float hld = hlv[l];
    float mx = -1e30f;
    for (int i = w; i < c; i += 4) {
        float v = h[(s + i) * 64 + l] * hld;
        #pragma unroll
        for (int off = 32; off; off >>= 1) v += __shfl_xor(v, off, 64);
        if (l == 0 && i < 768) els[i] = v;
        mx = fmaxf(mx, v);
    }
    if (l == 0) red[w] = mx;
    __syncthreads();
    if (tid == 0) bc[0] = fmaxf(fmaxf(red[0], red[1]), fmaxf(red[2], red[3]));
    __syncthreads();
    float m = bc[0];
    float ss = 0.f;
    for (int i = tid; i < cc; i += 256) {
        float a = expf(els[i] - m);
        els[i] = a;
        ss += a;
    }
    #pragma unroll
    for (int off = 32; off; off >>= 1) ss += __shfl_xor(ss, off, 64);
    if (l == 0) red[4 + w] = ss;
    __syncthreads();
    if (tid == 0) bc[1] = red[4] + red[5] + red[6] + red[7];
    __syncthreads();
    float asum = bc[1];
    float racc = 0.f;
    for (int i = w; i < cc; i += 4) racc += els[i] * h[(s + i) * 64 + l];
    accw[w][l] = racc;
    __syncthreads();
    if (w == 0) {
        float tot = accw[0][l] + accw[1][l] + accw[2][l] + accw[3][l];
        qstar[b * 128 + l] = hld;
        qstar[b * 128 + 64 + l] = tot / (asum + 1e-16f);
    }
}

extern "C" void kernel_launch(void* const* d_in, const int* in_sizes, int n_in,
                              void* d_out, int out_size, void* d_ws, size_t ws_size,
                              hipStream_t stream) {
    const float* x      = (const float*)d_in[0];
    const int*   ei     = (const int*)  d_in[1];
    const int*   batch  = (const int*)  d_in[2];
    const float* lin0_w = (const float*)d_in[3];
    const float* lin0_b = (const float*)d_in[4];
    const float* nn1_w  = (const float*)d_in[5];
    const float* nn1_b  = (const float*)d_in[6];
    const float* nn2_w  = (const float*)d_in[7];
    const float* nn2_b  = (const float*)d_in[8];
    const float* conv_b = (const float*)d_in[9];
    const float* gwih   = (const float*)d_in[10];
    const float* gwhh   = (const float*)d_in[11];
    const float* gbih   = (const float*)d_in[12];
    const float* gbhh   = (const float*)d_in[13];
    const float* lwih   = (const float*)d_in[14];
    const float* lwhh   = (const float*)d_in[15];
    const float* lbih   = (const float*)d_in[16];
    const float* lbhh   = (const float*)d_in[17];

    float* qstar = (float*)d_out;                 // [256*128]
    float* h     = (float*)d_out + NGB * 128;     // [N*64] == feat_map

    float* ws     = (float*)d_ws;
    float* W      = ws;                         // 4096
    float* agg    = ws + 4096;                  // N*64
    float* deg    = agg + NN * 64;              // N
    int*   cnt    = (int*)(deg + NN);           // 256
    int*   starts = cnt + 256;                  // 256
    float* hl     = (float*)(starts + 256);     // 256*64
    float* cl     = hl + NGB * 64;              // 256*64
    float* wihT   = cl + NGB * 64;              // 128*256
    float* whhT   = wihT + 128 * 256;           // 64*256
    unsigned int* P = (unsigned int*)(whhT + 64 * 256);  // 14336
    float* brz    = (float*)(P + 14336);        // 128

    hipMemsetAsync(deg, 0, NN * sizeof(float), stream);
    hipMemsetAsync(agg, 0, NN * 64 * sizeof(float), stream);   // once; k_update re-zeroes

    k_precompute_W<<<16, 256, 0, stream>>>(nn1_w, nn1_b, nn2_w, nn2_b, W);
    k_pack_mfma<<<56, 256, 0, stream>>>(W, gwih, gwhh, gbih, gbhh, P, brz);
    k_transpose_lstm<<<128, 256, 0, stream>>>(lwih, lwhh, wihT, whhT);
    k_deg<<<(NE + 255) / 256, 256, 0, stream>>>(ei, deg);
    k_bounds<<<1, 256, 0, stream>>>(batch, starts, cnt);
    k_lin0<<<(NN + 3) / 4, 256, 0, stream>>>(x, lin0_w, lin0_b, h);

    for (int it = 0; it < 3; ++it) {
        k_scatter<<<(NE * 64 + 255) / 256, 256, 0, stream>>>(ei, h, agg);
        k_update<<<782, 256, 0, stream>>>(agg, deg, P, conv_b, brz, gbih, gbhh, h, agg);
    }
    for (int st = 0; st < 3; ++st) {
        k_s2s<<<NGB, 256, 0, stream>>>(h, starts, cnt, wihT, whhT, lbih, lbhh,
                                       hl, cl, qstar, st == 0 ? 1 : 0);
    }
}

// Round 9
// 378.302 us; speedup vs baseline: 2.8902x; 1.0054x over previous
//
#include <hip/hip_runtime.h>
#include <math.h>

#define NN 50000
#define NE 60000
#define FIN 32
#define DIM 64
#define NGB 256   // graphs in batch

typedef short s8v __attribute__((ext_vector_type(8)));
typedef float f4v __attribute__((ext_vector_type(4)));

__device__ __forceinline__ float rl(float v, int lane) {
    return __int_as_float(__builtin_amdgcn_readlane(__float_as_int(v), lane));
}
__device__ __forceinline__ float sigm(float x) { return 1.f / (1.f + expf(-x)); }

// pack two f32 as bf16 (RTN-even) into one u32: a -> low16, b -> high16
__device__ __forceinline__ unsigned int pk2(float a, float b) {
    unsigned int ua = __float_as_uint(a);
    unsigned int ub = __float_as_uint(b);
    ua = (ua + 0x7FFFu + ((ua >> 16) & 1u)) >> 16;
    ub = (ub + 0x7FFFu + ((ub >> 16) & 1u)) & 0xFFFF0000u;
    return ua | ub;
}
__device__ __forceinline__ unsigned short pk1(float a) {
    unsigned int ua = __float_as_uint(a);
    return (unsigned short)((ua + 0x7FFFu + ((ua >> 16) & 1u)) >> 16);
}
__device__ __forceinline__ s8v as_s8(uint4 u) {
    union { uint4 a; s8v b; } c; c.a = u; return c.b;
}

// ---------------- precompute: W[i*64+o] = (relu(nn1_w + nn1_b) @ nn2_w^T + nn2_b)
__global__ void k_precompute_W(const float* __restrict__ nn1_w, const float* __restrict__ nn1_b,
                               const float* __restrict__ nn2_w, const float* __restrict__ nn2_b,
                               float* __restrict__ W) {
    __shared__ float t[64];
    int tid = threadIdx.x;
    if (tid < 64) t[tid] = fmaxf(nn1_w[tid] + nn1_b[tid], 0.f);
    __syncthreads();
    int k = blockIdx.x * blockDim.x + tid;   // 0..4095
    float acc = nn2_b[k];
    #pragma unroll
    for (int j = 0; j < 64; ++j) acc += t[j] * nn2_w[k * 64 + j];
    W[k] = acc;
}

// ---------------- pack weights into MFMA B-fragment layouts (bf16, XOR-swizzled)
// Regions in P (u32 index):
//   [0,2048)      WpA : W as B[k=0..63][col=0..63], col stride 128 B
//   [2048,10240)  B01 : [wih_r|z ; whh_r|z] as B[k=0..127][col=0..127], col stride 256 B
//   [10240,12288) BnI : wih_n as B[k][col], col stride 128 B
//   [12288,14336) BnH : whh_n as B[k][col], col stride 128 B
// Within a col's row, 16B slot at byte kk*2 stored at (kk*2) ^ ((col&7)<<4).
__global__ void k_pack_mfma(const float* __restrict__ W, const float* __restrict__ wih,
                            const float* __restrict__ whh, const float* __restrict__ bih,
                            const float* __restrict__ bhh, unsigned int* __restrict__ P,
                            float* __restrict__ brz) {
    int q = blockIdx.x * 256 + threadIdx.x;   // 56*256 = 14336
    if (q < 128) brz[q] = bih[q] + bhh[q];    // summed r,z biases
    if (q < 2048) {                           // WpA
        int byte = q * 4, col = byte >> 7, rem = byte & 127;
        int lin = rem ^ ((col & 7) << 4);
        int k0 = (lin >> 4) * 8 + ((lin >> 2) & 3) * 2;
        P[q] = pk2(W[k0 * 64 + col], W[(k0 + 1) * 64 + col]);
    } else if (q < 10240) {                   // B01 (K=128)
        int w = q - 2048, byte = w * 4, col = byte >> 8, rem = byte & 255;
        int lin = rem ^ ((col & 7) << 4);
        int k0 = (lin >> 4) * 8 + ((lin >> 2) & 3) * 2;
        int g = col >> 6, o = col & 63;
        int rowbase = (g * 64 + o) * 64;
        const float* src = (k0 >= 64) ? whh : wih;
        int kk = (k0 >= 64) ? k0 - 64 : k0;
        P[q] = pk2(src[rowbase + kk], src[rowbase + kk + 1]);
    } else if (q < 12288) {                   // BnI
        int w = q - 10240, byte = w * 4, col = byte >> 7, rem = byte & 127;
        int lin = rem ^ ((col & 7) << 4);
        int k0 = (lin >> 4) * 8 + ((lin >> 2) & 3) * 2;
        P[q] = pk2(wih[(128 + col) * 64 + k0], wih[(128 + col) * 64 + k0 + 1]);
    } else {                                  // BnH
        int w = q - 12288, byte = w * 4, col = byte >> 7, rem = byte & 127;
        int lin = rem ^ ((col & 7) << 4);
        int k0 = (lin >> 4) * 8 + ((lin >> 2) & 3) * 2;
        P[q] = pk2(whh[(128 + col) * 64 + k0], whh[(128 + col) * 64 + k0 + 1]);
    }
}

// ---------------- transpose LSTM weights for coalesced gate dots
__global__ void k_transpose_lstm(const float* __restrict__ wih, const float* __restrict__ whh,
                                 float* __restrict__ wihT, float* __restrict__ whhT) {
    int p = blockIdx.x * 256 + threadIdx.x;
    if (p < 256 * 128) { int o = p >> 7, k = p & 127; wihT[k * 256 + o] = wih[p]; }
    if (p < 256 * 64)  { int o = p >> 6, k = p & 63;  whhT[k * 256 + o] = whh[p]; }
}

// ---------------- degree over dst (edge atomics only; low contention)
__global__ void k_deg(const int* __restrict__ ei, float* __restrict__ deg) {
    int i = blockIdx.x * 256 + threadIdx.x;
    if (i < NE) atomicAdd(&deg[ei[NE + i]], 1.0f);
}

// ---------------- per-graph starts/cnt via binary search on sorted batch (no atomics)
__global__ void k_bounds(const int* __restrict__ batch, int* __restrict__ starts,
                         int* __restrict__ cnt) {
    __shared__ int sLB[257];
    int b = threadIdx.x;   // 0..255
    int lo = 0, hi = NN;
    while (lo < hi) {      // lower_bound(batch, b)
        int mid = (lo + hi) >> 1;
        if (batch[mid] < b) lo = mid + 1; else hi = mid;
    }
    sLB[b] = lo;
    if (b == 0) sLB[256] = NN;
    __syncthreads();
    starts[b] = sLB[b];
    cnt[b] = sLB[b + 1] - sLB[b];
}

// ---------------- lin0: h = relu(x @ lin0_w^T + b), 64 lanes per node
// Staging writes are LINEAR in wT (conflict-free); strided 8 KB global read is L2-hit.
__global__ void k_lin0(const float* __restrict__ x, const float* __restrict__ w,
                       const float* __restrict__ b, float* __restrict__ h) {
    __shared__ float wT[FIN * 64];   // wT[k*64+o] = w[o*32+k]
    int tid = threadIdx.x;
    for (int p = tid; p < FIN * 64; p += 256) {
        int k = p >> 6, o = p & 63;          // p = k*64+o -> linear LDS write
        wT[p] = w[o * FIN + k];
    }
    __syncthreads();
    int l = tid & 63;
    int n = blockIdx.x * 4 + (tid >> 6);
    if (n >= NN) return;
    float xv = x[n * FIN + (l & 31)];
    float acc = b[l];
    #pragma unroll
    for (int k = 0; k < FIN; ++k) {
        float xk = rl(xv, k);
        acc += xk * wT[k * 64 + l];
    }
    h[n * 64 + l] = fmaxf(acc, 0.f);
}

// ---------------- scatter: agg[dst] += h[src]  (64 lanes per edge)
__global__ void k_scatter(const int* __restrict__ ei, const float* __restrict__ h,
                          float* __restrict__ agg) {
    int gid = blockIdx.x * 256 + threadIdx.x;
    int e = gid >> 6, l = gid & 63;
    if (e >= NE) return;
    int s = ei[e], d = ei[NE + e];
    atomicAdd(&agg[d * 64 + l], h[s * 64 + l]);
}

// ---------------- MFMA conv(W)+GRU node update. Wave = 16 nodes, block = 4 waves.
// LDS: 56 KB pre-packed bf16 weights (straight copy) + 4 x 2 KB per-wave m-transpose.
// Re-zeroes agg after reading (each element exactly once).
__global__ void __launch_bounds__(256) k_update(
    const float* __restrict__ agg, const float* __restrict__ deg,
    const unsigned int* __restrict__ P, const float* __restrict__ conv_b,
    const float* __restrict__ brz, const float* __restrict__ bih, const float* __restrict__ bhh,
    float* __restrict__ h, float* __restrict__ aggz) {
    __shared__ unsigned int L[16384];   // 64 KB
    int tid = threadIdx.x;
    #pragma unroll
    for (int p = 0; p < 14336; p += 256) L[p + tid] = P[p + tid];
    __syncthreads();

    int l = tid & 63;
    int w = tid >> 6;
    int nb = (blockIdx.x * 4 + w) * 16;
    if (nb >= NN) return;               // idle waves in last block (after barrier)
    int row = l & 15, kq = l >> 4;      // A/B frag: row/col = lane&15, k-chunk = lane>>4
    int node = nb + row;

    float dv = deg[node];
    float inv = dv > 0.f ? 1.f / dv : 0.f;

    // ---- A-frags of agg_mean (bf16), zero agg behind us
    uint4 aA[2];
    #pragma unroll
    for (int kt = 0; kt < 2; ++kt) {
        const float4* src = (const float4*)(agg + node * 64 + kt * 32 + kq * 8);
        float4 x0 = src[0], x1 = src[1];
        float4 z4 = {0.f, 0.f, 0.f, 0.f};
        ((float4*)(aggz + node * 64 + kt * 32 + kq * 8))[0] = z4;
        ((float4*)(aggz + node * 64 + kt * 32 + kq * 8))[1] = z4;
        aA[kt].x = pk2(x0.x * inv, x0.y * inv);
        aA[kt].y = pk2(x0.z * inv, x0.w * inv);
        aA[kt].z = pk2(x1.x * inv, x1.y * inv);
        aA[kt].w = pk2(x1.z * inv, x1.w * inv);
    }

    // ---- stage A: m = relu(aggmean @ W + conv_b)
    f4v mC[4];
    #pragma unroll
    for (int ct = 0; ct < 4; ++ct) {
        f4v acc = {0.f, 0.f, 0.f, 0.f};
        int col = ct * 16 + row;
        #pragma unroll
        for (int kt = 0; kt < 2; ++kt) {
            int boff = col * 128 + ((kt * 64 + kq * 16) ^ ((col & 7) << 4));
            uint4 b = *(const uint4*)((const char*)L + boff);
            acc = __builtin_amdgcn_mfma_f32_16x16x32_bf16(as_s8(aA[kt]), as_s8(b), acc, 0, 0, 0);
        }
        mC[ct] = acc;
    }

    // ---- transpose m to A-frag layout via per-wave LDS region (swizzled)
    int mbase = 57344 + w * 2048;
    #pragma unroll
    for (int ct = 0; ct < 4; ++ct) {
        int ch = ct * 16 + row;
        float cb = conv_b[ch];
        #pragma unroll
        for (int r = 0; r < 4; ++r) {
            float mval = fmaxf(mC[ct][r] + cb, 0.f);
            int nrow = kq * 4 + r;
            int off = mbase + ((nrow * 128 + ch * 2) ^ ((nrow & 7) << 4));
            *(unsigned short*)((char*)L + off) = pk1(mval);
        }
    }
    // same-wave DS ordering: reads below see the writes above (no block barrier needed)
    uint4 mA[2], hA[2];
    #pragma unroll
    for (int kt = 0; kt < 2; ++kt) {
        int off = mbase + ((row * 128 + kt * 64 + kq * 16) ^ ((row & 7) << 4));
        mA[kt] = *(const uint4*)((const char*)L + off);
        const float4* hs = (const float4*)(h + node * 64 + kt * 32 + kq * 8);
        float4 y0 = hs[0], y1 = hs[1];
        hA[kt].x = pk2(y0.x, y0.y);
        hA[kt].y = pk2(y0.z, y0.w);
        hA[kt].z = pk2(y1.x, y1.y);
        hA[kt].w = pk2(y1.z, y1.w);
    }

    // ---- gates r,z: [m|h](16x128) @ B01(128x128)
    f4v g01[8];
    #pragma unroll
    for (int ct = 0; ct < 8; ++ct) {
        f4v acc = {0.f, 0.f, 0.f, 0.f};
        int col = ct * 16 + row;
        #pragma unroll
        for (int kt = 0; kt < 4; ++kt) {
            uint4 a = (kt < 2) ? mA[kt] : hA[kt - 2];
            int boff = 8192 + col * 256 + ((kt * 64 + kq * 16) ^ ((col & 7) << 4));
            uint4 b = *(const uint4*)((const char*)L + boff);
            acc = __builtin_amdgcn_mfma_f32_16x16x32_bf16(as_s8(a), as_s8(b), acc, 0, 0, 0);
        }
        g01[ct] = acc;
    }
    // ---- i_n = m @ wih_n^T ; h_n = h @ whh_n^T
    f4v gin[4], ghn[4];
    #pragma unroll
    for (int ct = 0; ct < 4; ++ct) {
        f4v ai = {0.f, 0.f, 0.f, 0.f}, ah = {0.f, 0.f, 0.f, 0.f};
        int col = ct * 16 + row;
        #pragma unroll
        for (int kt = 0; kt < 2; ++kt) {
            int swz = (kt * 64 + kq * 16) ^ ((col & 7) << 4);
            uint4 bi = *(const uint4*)((const char*)L + 40960 + col * 128 + swz);
            uint4 bh = *(const uint4*)((const char*)L + 49152 + col * 128 + swz);
            ai = __builtin_amdgcn_mfma_f32_16x16x32_bf16(as_s8(mA[kt]), as_s8(bi), ai, 0, 0, 0);
            ah = __builtin_amdgcn_mfma_f32_16x16x32_bf16(as_s8(hA[kt]), as_s8(bh), ah, 0, 0, 0);
        }
        gin[ct] = ai; ghn[ct] = ah;
    }

    // ---- epilogue: GRU cell in C-frag layout (col=lane&15, row=(lane>>4)*4+r)
    #pragma unroll
    for (int ct = 0; ct < 4; ++ct) {
        int ch = ct * 16 + row;
        float br = brz[ch], bz = brz[64 + ch];
        float bin = bih[128 + ch], bhn = bhh[128 + ch];
        #pragma unroll
        for (int r = 0; r < 4; ++r) {
            int n2 = nb + kq * 4 + r;
            float rg = sigm(g01[ct][r] + br);
            float zg = sigm(g01[4 + ct][r] + bz);
            float ng = tanhf(gin[ct][r] + bin + rg * (ghn[ct][r] + bhn));
            float hold = h[n2 * 64 + ch];
            h[n2 * 64 + ch] = (1.f - zg) * ng + zg * hold;
        }
    }
}

// ---------------- fused Set2Set step: LSTM + segment softmax + weighted sum.
__global__ void k_s2s(const float* __restrict__ h, const int* __restrict__ starts,
                      const int* __restrict__ cnt, const float* __restrict__ wihT,
                      const float* __restrict__ whhT, const float* __restrict__ bih,
                      const float* __restrict__ bhh, float* __restrict__ hl,
                      float* __restrict__ cl, float* __restrict__ qstar, int first) {
    __shared__ float ga[256];
    __shared__ float hlv[64];
    __shared__ float els[768];
    __shared__ float red[8];
    __shared__ float bc[2];
    __shared__ float accw[4][64];
    int b = blockIdx.x, tid = threadIdx.x, w = tid >> 6, l = tid & 63;

    if (first) {
        if (tid < 64) {   // q_star = 0, hl = 0, cl = 0 -> gates are biases only
            float ig = sigm(bih[tid] + bhh[tid]);
            float gg = tanhf(bih[128 + tid] + bhh[128 + tid]);
            float og = sigm(bih[192 + tid] + bhh[192 + tid]);
            float c = ig * gg;
            cl[b * 64 + tid] = c;
            float hh = og * tanhf(c);
            hl[b * 64 + tid] = hh;
            hlv[tid] = hh;
        }
    } else {
        const float* qs = qstar + b * 128;
        const float* hb = hl + b * 64;
        float a = bih[tid] + bhh[tid];
        for (int k = 0; k < 128; ++k) a += qs[k] * wihT[k * 256 + tid];
        for (int k = 0; k < 64; ++k)  a += hb[k] * whhT[k * 256 + tid];
        ga[tid] = a;
        __syncthreads();
        if (tid < 64) {
            float c = sigm(ga[64 + tid]) * cl[b * 64 + tid] + sigm(ga[tid]) * tanhf(ga[128 + tid]);
            cl[b * 64 + tid] = c;
            float hh = sigm(ga[192 + tid]) * tanhf(c);
            hl[b * 64 + tid] = hh;
            hlv[tid] = hh;
        }
    }
    __syncthreads();

    int s = starts[b], c = cnt[b];
    int cc = c < 768 ? c : 768;
    float hld = hlv[l];
    float mx = -1e30f;
    for (int i = w; i < c; i += 4) {
        float v = h[(s + i) * 64 + l] * hld;
        #pragma unroll
        for (int off = 32; off; off >>= 1) v += __shfl_xor(v, off, 64);
        if (l == 0 && i < 768) els[i] = v;
        mx = fmaxf(mx, v);
    }
    if (l == 0) red[w] = mx;
    __syncthreads();
    if (tid == 0) bc[0] = fmaxf(fmaxf(red[0], red[1]), fmaxf(red[2], red[3]));
    __syncthreads();
    float m = bc[0];
    float ss = 0.f;
    for (int i = tid; i < cc; i += 256) {
        float a = expf(els[i] - m);
        els[i] = a;
        ss += a;
    }
    #pragma unroll
    for (int off = 32; off; off >>= 1) ss += __shfl_xor(ss, off, 64);
    if (l == 0) red[4 + w] = ss;
    __syncthreads();
    if (tid == 0) bc[1] = red[4] + red[5] + red[6] + red[7];
    __syncthreads();
    float asum = bc[1];
    float racc = 0.f;
    for (int i = w; i < cc; i += 4) racc += els[i] * h[(s + i) * 64 + l];
    accw[w][l] = racc;
    __syncthreads();
    if (w == 0) {
        float tot = accw[0][l] + accw[1][l] + accw[2][l] + accw[3][l];
        qstar[b * 128 + l] = hld;
        qstar[b * 128 + 64 + l] = tot / (asum + 1e-16f);
    }
}

extern "C" void kernel_launch(void* const* d_in, const int* in_sizes, int n_in,
                              void* d_out, int out_size, void* d_ws, size_t ws_size,
                              hipStream_t stream) {
    const float* x      = (const float*)d_in[0];
    const int*   ei     = (const int*)  d_in[1];
    const int*   batch  = (const int*)  d_in[2];
    const float* lin0_w = (const float*)d_in[3];
    const float* lin0_b = (const float*)d_in[4];
    const float* nn1_w  = (const float*)d_in[5];
    const float* nn1_b  = (const float*)d_in[6];
    const float* nn2_w  = (const float*)d_in[7];
    const float* nn2_b  = (const float*)d_in[8];
    const float* conv_b = (const float*)d_in[9];
    const float* gwih   = (const float*)d_in[10];
    const float* gwhh   = (const float*)d_in[11];
    const float* gbih   = (const float*)d_in[12];
    const float* gbhh   = (const float*)d_in[13];
    const float* lwih   = (const float*)d_in[14];
    const float* lwhh   = (const float*)d_in[15];
    const float* lbih   = (const float*)d_in[16];
    const float* lbhh   = (const float*)d_in[17];

    float* qstar = (float*)d_out;                 // [256*128]
    float* h     = (float*)d_out + NGB * 128;     // [N*64] == feat_map

    float* ws     = (float*)d_ws;
    float* W      = ws;                         // 4096
    float* agg    = ws + 4096;                  // N*64
    float* deg    = agg + NN * 64;              // N
    int*   cnt    = (int*)(deg + NN);           // 256
    int*   starts = cnt + 256;                  // 256
    float* hl     = (float*)(starts + 256);     // 256*64
    float* cl     = hl + NGB * 64;              // 256*64
    float* wihT   = cl + NGB * 64;              // 128*256
    float* whhT   = wihT + 128 * 256;           // 64*256
    unsigned int* P = (unsigned int*)(whhT + 64 * 256);  // 14336
    float* brz    = (float*)(P + 14336);        // 128

    hipMemsetAsync(deg, 0, NN * sizeof(float), stream);
    hipMemsetAsync(agg, 0, NN * 64 * sizeof(float), stream);   // once; k_update re-zeroes

    k_precompute_W<<<16, 256, 0, stream>>>(nn1_w, nn1_b, nn2_w, nn2_b, W);
    k_pack_mfma<<<56, 256, 0, stream>>>(W, gwih, gwhh, gbih, gbhh, P, brz);
    k_transpose_lstm<<<128, 256, 0, stream>>>(lwih, lwhh, wihT, whhT);
    k_deg<<<(NE + 255) / 256, 256, 0, stream>>>(ei, deg);
    k_bounds<<<1, 256, 0, stream>>>(batch, starts, cnt);
    k_lin0<<<(NN + 3) / 4, 256, 0, stream>>>(x, lin0_w, lin0_b, h);

    for (int it = 0; it < 3; ++it) {
        k_scatter<<<(NE * 64 + 255) / 256, 256, 0, stream>>>(ei, h, agg);
        k_update<<<782, 256, 0, stream>>>(agg, deg, P, conv_b, brz, gbih, gbhh, h, agg);
    }
    for (int st = 0; st < 3; ++st) {
        k_s2s<<<NGB, 256, 0, stream>>>(h, starts, cnt, wihT, whhT, lbih, lbhh,
                                       hl, cl, qstar, st == 0 ? 1 : 0);
    }
}

// Round 10
// 343.224 us; speedup vs baseline: 3.1856x; 1.1022x over previous
//
#include <hip/hip_runtime.h>
#include <math.h>

#define NN 50000
#define NE 60000
#define FIN 32
#define DIM 64
#define NGB 256   // graphs in batch

typedef short s8v __attribute__((ext_vector_type(8)));
typedef float f4v __attribute__((ext_vector_type(4)));

__device__ __forceinline__ float rl(float v, int lane) {
    return __int_as_float(__builtin_amdgcn_readlane(__float_as_int(v), lane));
}
__device__ __forceinline__ float sigm(float x) { return 1.f / (1.f + expf(-x)); }

// pack two f32 as bf16 (RTN-even) into one u32: a -> low16, b -> high16
__device__ __forceinline__ unsigned int pk2(float a, float b) {
    unsigned int ua = __float_as_uint(a);
    unsigned int ub = __float_as_uint(b);
    ua = (ua + 0x7FFFu + ((ua >> 16) & 1u)) >> 16;
    ub = (ub + 0x7FFFu + ((ub >> 16) & 1u)) & 0xFFFF0000u;
    return ua | ub;
}
__device__ __forceinline__ unsigned short pk1(float a) {
    unsigned int ua = __float_as_uint(a);
    return (unsigned short)((ua + 0x7FFFu + ((ua >> 16) & 1u)) >> 16);
}
__device__ __forceinline__ s8v as_s8(uint4 u) {
    union { uint4 a; s8v b; } c; c.a = u; return c.b;
}

// ---------------- precompute: W[i*64+o] = (relu(nn1_w + nn1_b) @ nn2_w^T + nn2_b)
__global__ void k_precompute_W(const float* __restrict__ nn1_w, const float* __restrict__ nn1_b,
                               const float* __restrict__ nn2_w, const float* __restrict__ nn2_b,
                               float* __restrict__ W) {
    __shared__ float t[64];
    int tid = threadIdx.x;
    if (tid < 64) t[tid] = fmaxf(nn1_w[tid] + nn1_b[tid], 0.f);
    __syncthreads();
    int k = blockIdx.x * blockDim.x + tid;   // 0..4095
    float acc = nn2_b[k];
    #pragma unroll
    for (int j = 0; j < 64; ++j) acc += t[j] * nn2_w[k * 64 + j];
    W[k] = acc;
}

// ---------------- pack weights into MFMA B-fragment layouts (bf16, XOR-swizzled)
// Regions in P (u32 index):
//   [0,2048)      WpA : W as B[k=0..63][col=0..63], col stride 128 B
//   [2048,10240)  B01 : [wih_r|z ; whh_r|z] as B[k=0..127][col=0..127], col stride 256 B
//   [10240,12288) BnI : wih_n as B[k][col], col stride 128 B
//   [12288,14336) BnH : whh_n as B[k][col], col stride 128 B
// Within a col's row, 16B slot at byte kk*2 stored at (kk*2) ^ ((col&7)<<4).
__global__ void k_pack_mfma(const float* __restrict__ W, const float* __restrict__ wih,
                            const float* __restrict__ whh, const float* __restrict__ bih,
                            const float* __restrict__ bhh, unsigned int* __restrict__ P,
                            float* __restrict__ brz) {
    int q = blockIdx.x * 256 + threadIdx.x;   // 56*256 = 14336
    if (q < 128) brz[q] = bih[q] + bhh[q];    // summed r,z biases
    if (q < 2048) {                           // WpA
        int byte = q * 4, col = byte >> 7, rem = byte & 127;
        int lin = rem ^ ((col & 7) << 4);
        int k0 = (lin >> 4) * 8 + ((lin >> 2) & 3) * 2;
        P[q] = pk2(W[k0 * 64 + col], W[(k0 + 1) * 64 + col]);
    } else if (q < 10240) {                   // B01 (K=128)
        int w = q - 2048, byte = w * 4, col = byte >> 8, rem = byte & 255;
        int lin = rem ^ ((col & 7) << 4);
        int k0 = (lin >> 4) * 8 + ((lin >> 2) & 3) * 2;
        int g = col >> 6, o = col & 63;
        int rowbase = (g * 64 + o) * 64;
        const float* src = (k0 >= 64) ? whh : wih;
        int kk = (k0 >= 64) ? k0 - 64 : k0;
        P[q] = pk2(src[rowbase + kk], src[rowbase + kk + 1]);
    } else if (q < 12288) {                   // BnI
        int w = q - 10240, byte = w * 4, col = byte >> 7, rem = byte & 127;
        int lin = rem ^ ((col & 7) << 4);
        int k0 = (lin >> 4) * 8 + ((lin >> 2) & 3) * 2;
        P[q] = pk2(wih[(128 + col) * 64 + k0], wih[(128 + col) * 64 + k0 + 1]);
    } else {                                  // BnH
        int w = q - 12288, byte = w * 4, col = byte >> 7, rem = byte & 127;
        int lin = rem ^ ((col & 7) << 4);
        int k0 = (lin >> 4) * 8 + ((lin >> 2) & 3) * 2;
        P[q] = pk2(whh[(128 + col) * 64 + k0], whh[(128 + col) * 64 + k0 + 1]);
    }
}

// ---------------- transpose LSTM weights for coalesced gate dots
__global__ void k_transpose_lstm(const float* __restrict__ wih, const float* __restrict__ whh,
                                 float* __restrict__ wihT, float* __restrict__ whhT) {
    int p = blockIdx.x * 256 + threadIdx.x;
    if (p < 256 * 128) { int o = p >> 7, k = p & 127; wihT[k * 256 + o] = wih[p]; }
    if (p < 256 * 64)  { int o = p >> 6, k = p & 63;  whhT[k * 256 + o] = whh[p]; }
}

// ---------------- degree over dst (edge atomics only; low contention)
__global__ void k_deg(const int* __restrict__ ei, float* __restrict__ deg) {
    int i = blockIdx.x * 256 + threadIdx.x;
    if (i < NE) atomicAdd(&deg[ei[NE + i]], 1.0f);
}

// ---------------- per-graph starts/cnt via binary search on sorted batch (no atomics)
__global__ void k_bounds(const int* __restrict__ batch, int* __restrict__ starts,
                         int* __restrict__ cnt) {
    __shared__ int sLB[257];
    int b = threadIdx.x;   // 0..255
    int lo = 0, hi = NN;
    while (lo < hi) {      // lower_bound(batch, b)
        int mid = (lo + hi) >> 1;
        if (batch[mid] < b) lo = mid + 1; else hi = mid;
    }
    sLB[b] = lo;
    if (b == 0) sLB[256] = NN;
    __syncthreads();
    starts[b] = sLB[b];
    cnt[b] = sLB[b + 1] - sLB[b];
}

// ---------------- lin0: h = relu(x @ lin0_w^T + b); grid-stride, weights staged ONCE
// per block (512 blocks). 1 wave = 1 node per iteration, 2-node unroll for ILP.
__global__ void k_lin0(const float* __restrict__ x, const float* __restrict__ w,
                       const float* __restrict__ b, float* __restrict__ h) {
    __shared__ float wT[FIN * 64];   // wT[k*64+o] = w[o*32+k]
    int tid = threadIdx.x;
    for (int p = tid; p < FIN * 64; p += 256) {
        int k = p >> 6, o = p & 63;          // linear LDS write, strided L2-hit read
        wT[p] = w[o * FIN + k];
    }
    __syncthreads();
    int l = tid & 63;
    float bl = b[l];
    int wave = blockIdx.x * 4 + (tid >> 6);
    int nwaves = gridDim.x * 4;
    for (int n0 = wave * 2; n0 < NN; n0 += nwaves * 2) {   // NN even: both nodes valid
        float xv0 = x[n0 * FIN + (l & 31)];
        float xv1 = x[(n0 + 1) * FIN + (l & 31)];
        float a0 = bl, a1 = bl;
        #pragma unroll
        for (int k = 0; k < FIN; ++k) {
            float wk = wT[k * 64 + l];
            a0 += rl(xv0, k) * wk;
            a1 += rl(xv1, k) * wk;
        }
        h[n0 * 64 + l] = fmaxf(a0, 0.f);
        h[(n0 + 1) * 64 + l] = fmaxf(a1, 0.f);
    }
}

// ---------------- scatter: agg[dst] += h[src]  (64 lanes per edge)
__global__ void k_scatter(const int* __restrict__ ei, const float* __restrict__ h,
                          float* __restrict__ agg) {
    int gid = blockIdx.x * 256 + threadIdx.x;
    int e = gid >> 6, l = gid & 63;
    if (e >= NE) return;
    int s = ei[e], d = ei[NE + e];
    atomicAdd(&agg[d * 64 + l], h[s * 64 + l]);
}

// ---------------- MFMA conv(W)+GRU node update. Wave = 16 nodes, block = 4 waves.
// LDS: 56 KB pre-packed bf16 weights (straight copy) + 4 x 2 KB per-wave m-transpose.
// Re-zeroes agg after reading (each element exactly once).
__global__ void __launch_bounds__(256) k_update(
    const float* __restrict__ agg, const float* __restrict__ deg,
    const unsigned int* __restrict__ P, const float* __restrict__ conv_b,
    const float* __restrict__ brz, const float* __restrict__ bih, const float* __restrict__ bhh,
    float* __restrict__ h, float* __restrict__ aggz) {
    __shared__ unsigned int L[16384];   // 64 KB
    int tid = threadIdx.x;
    #pragma unroll
    for (int p = 0; p < 14336; p += 256) L[p + tid] = P[p + tid];
    __syncthreads();

    int l = tid & 63;
    int w = tid >> 6;
    int nb = (blockIdx.x * 4 + w) * 16;
    if (nb >= NN) return;               // idle waves in last block (after barrier)
    int row = l & 15, kq = l >> 4;      // A/B frag: row/col = lane&15, k-chunk = lane>>4
    int node = nb + row;

    float dv = deg[node];
    float inv = dv > 0.f ? 1.f / dv : 0.f;

    // ---- A-frags of agg_mean (bf16), zero agg behind us
    uint4 aA[2];
    #pragma unroll
    for (int kt = 0; kt < 2; ++kt) {
        const float4* src = (const float4*)(agg + node * 64 + kt * 32 + kq * 8);
        float4 x0 = src[0], x1 = src[1];
        float4 z4 = {0.f, 0.f, 0.f, 0.f};
        ((float4*)(aggz + node * 64 + kt * 32 + kq * 8))[0] = z4;
        ((float4*)(aggz + node * 64 + kt * 32 + kq * 8))[1] = z4;
        aA[kt].x = pk2(x0.x * inv, x0.y * inv);
        aA[kt].y = pk2(x0.z * inv, x0.w * inv);
        aA[kt].z = pk2(x1.x * inv, x1.y * inv);
        aA[kt].w = pk2(x1.z * inv, x1.w * inv);
    }

    // ---- stage A: m = relu(aggmean @ W + conv_b)
    f4v mC[4];
    #pragma unroll
    for (int ct = 0; ct < 4; ++ct) {
        f4v acc = {0.f, 0.f, 0.f, 0.f};
        int col = ct * 16 + row;
        #pragma unroll
        for (int kt = 0; kt < 2; ++kt) {
            int boff = col * 128 + ((kt * 64 + kq * 16) ^ ((col & 7) << 4));
            uint4 b = *(const uint4*)((const char*)L + boff);
            acc = __builtin_amdgcn_mfma_f32_16x16x32_bf16(as_s8(aA[kt]), as_s8(b), acc, 0, 0, 0);
        }
        mC[ct] = acc;
    }

    // ---- transpose m to A-frag layout via per-wave LDS region (swizzled)
    int mbase = 57344 + w * 2048;
    #pragma unroll
    for (int ct = 0; ct < 4; ++ct) {
        int ch = ct * 16 + row;
        float cb = conv_b[ch];
        #pragma unroll
        for (int r = 0; r < 4; ++r) {
            float mval = fmaxf(mC[ct][r] + cb, 0.f);
            int nrow = kq * 4 + r;
            int off = mbase + ((nrow * 128 + ch * 2) ^ ((nrow & 7) << 4));
            *(unsigned short*)((char*)L + off) = pk1(mval);
        }
    }
    // same-wave DS ordering: reads below see the writes above (no block barrier needed)
    uint4 mA[2], hA[2];
    #pragma unroll
    for (int kt = 0; kt < 2; ++kt) {
        int off = mbase + ((row * 128 + kt * 64 + kq * 16) ^ ((row & 7) << 4));
        mA[kt] = *(const uint4*)((const char*)L + off);
        const float4* hs = (const float4*)(h + node * 64 + kt * 32 + kq * 8);
        float4 y0 = hs[0], y1 = hs[1];
        hA[kt].x = pk2(y0.x, y0.y);
        hA[kt].y = pk2(y0.z, y0.w);
        hA[kt].z = pk2(y1.x, y1.y);
        hA[kt].w = pk2(y1.z, y1.w);
    }

    // ---- gates r,z: [m|h](16x128) @ B01(128x128)
    f4v g01[8];
    #pragma unroll
    for (int ct = 0; ct < 8; ++ct) {
        f4v acc = {0.f, 0.f, 0.f, 0.f};
        int col = ct * 16 + row;
        #pragma unroll
        for (int kt = 0; kt < 4; ++kt) {
            uint4 a = (kt < 2) ? mA[kt] : hA[kt - 2];
            int boff = 8192 + col * 256 + ((kt * 64 + kq * 16) ^ ((col & 7) << 4));
            uint4 b = *(const uint4*)((const char*)L + boff);
            acc = __builtin_amdgcn_mfma_f32_16x16x32_bf16(as_s8(a), as_s8(b), acc, 0, 0, 0);
        }
        g01[ct] = acc;
    }
    // ---- i_n = m @ wih_n^T ; h_n = h @ whh_n^T
    f4v gin[4], ghn[4];
    #pragma unroll
    for (int ct = 0; ct < 4; ++ct) {
        f4v ai = {0.f, 0.f, 0.f, 0.f}, ah = {0.f, 0.f, 0.f, 0.f};
        int col = ct * 16 + row;
        #pragma unroll
        for (int kt = 0; kt < 2; ++kt) {
            int swz = (kt * 64 + kq * 16) ^ ((col & 7) << 4);
            uint4 bi = *(const uint4*)((const char*)L + 40960 + col * 128 + swz);
            uint4 bh = *(const uint4*)((const char*)L + 49152 + col * 128 + swz);
            ai = __builtin_amdgcn_mfma_f32_16x16x32_bf16(as_s8(mA[kt]), as_s8(bi), ai, 0, 0, 0);
            ah = __builtin_amdgcn_mfma_f32_16x16x32_bf16(as_s8(hA[kt]), as_s8(bh), ah, 0, 0, 0);
        }
        gin[ct] = ai; ghn[ct] = ah;
    }

    // ---- epilogue: GRU cell in C-frag layout (col=lane&15, row=(lane>>4)*4+r)
    #pragma unroll
    for (int ct = 0; ct < 4; ++ct) {
        int ch = ct * 16 + row;
        float br = brz[ch], bz = brz[64 + ch];
        float bin = bih[128 + ch], bhn = bhh[128 + ch];
        #pragma unroll
        for (int r = 0; r < 4; ++r) {
            int n2 = nb + kq * 4 + r;
            float rg = sigm(g01[ct][r] + br);
            float zg = sigm(g01[4 + ct][r] + bz);
            float ng = tanhf(gin[ct][r] + bin + rg * (ghn[ct][r] + bhn));
            float hold = h[n2 * 64 + ch];
            h[n2 * 64 + ch] = (1.f - zg) * ng + zg * hold;
        }
    }
}

// ---------------- fused Set2Set step: LSTM + segment softmax + weighted sum.
__global__ void k_s2s(const float* __restrict__ h, const int* __restrict__ starts,
                      const int* __restrict__ cnt, const float* __restrict__ wihT,
                      const float* __restrict__ whhT, const float* __restrict__ bih,
                      const float* __restrict__ bhh, float* __restrict__ hl,
                      float* __restrict__ cl, float* __restrict__ qstar, int first) {
    __shared__ float ga[256];
    __shared__ float hlv[64];
    __shared__ float els[768];
    __shared__ float red[8];
    __shared__ float bc[2];
    __shared__ float accw[4][64];
    int b = blockIdx.x, tid = threadIdx.x, w = tid >> 6, l = tid & 63;

    if (first) {
        if (tid < 64) {   // q_star = 0, hl = 0, cl = 0 -> gates are biases only
            float ig = sigm(bih[tid] + bhh[tid]);
            float gg = tanhf(bih[128 + tid] + bhh[128 + tid]);
            float og = sigm(bih[192 + tid] + bhh[192 + tid]);
            float c = ig * gg;
            cl[b * 64 + tid] = c;
            float hh = og * tanhf(c);
            hl[b * 64 + tid] = hh;
            hlv[tid] = hh;
        }
    } else {
        const float* qs = qstar + b * 128;
        const float* hb = hl + b * 64;
        float a = bih[tid] + bhh[tid];
        for (int k = 0; k < 128; ++k) a += qs[k] * wihT[k * 256 + tid];
        for (int k = 0; k < 64; ++k)  a += hb[k] * whhT[k * 256 + tid];
        ga[tid] = a;
        __syncthreads();
        if (tid < 64) {
            float c = sigm(ga[64 + tid]) * cl[b * 64 + tid] + sigm(ga[tid]) * tanhf(ga[128 + tid]);
            cl[b * 64 + tid] = c;
            float hh = sigm(ga[192 + tid]) * tanhf(c);
            hl[b * 64 + tid] = hh;
            hlv[tid] = hh;
        }
    }
    __syncthreads();

    int s = starts[b], c = cnt[b];
    int cc = c < 768 ? c : 768;
    float hld = hlv[l];
    float mx = -1e30f;
    for (int i = w; i < c; i += 4) {
        float v = h[(s + i) * 64 + l] * hld;
        #pragma unroll
        for (int off = 32; off; off >>= 1) v += __shfl_xor(v, off, 64);
        if (l == 0 && i < 768) els[i] = v;
        mx = fmaxf(mx, v);
    }
    if (l == 0) red[w] = mx;
    __syncthreads();
    if (tid == 0) bc[0] = fmaxf(fmaxf(red[0], red[1]), fmaxf(red[2], red[3]));
    __syncthreads();
    float m = bc[0];
    float ss = 0.f;
    for (int i = tid; i < cc; i += 256) {
        float a = expf(els[i] - m);
        els[i] = a;
        ss += a;
    }
    #pragma unroll
    for (int off = 32; off; off >>= 1) ss += __shfl_xor(ss, off, 64);
    if (l == 0) red[4 + w] = ss;
    __syncthreads();
    if (tid == 0) bc[1] = red[4] + red[5] + red[6] + red[7];
    __syncthreads();
    float asum = bc[1];
    float racc = 0.f;
    for (int i = w; i < cc; i += 4) racc += els[i] * h[(s + i) * 64 + l];
    accw[w][l] = racc;
    __syncthreads();
    if (w == 0) {
        float tot = accw[0][l] + accw[1][l] + accw[2][l] + accw[3][l];
        qstar[b * 128 + l] = hld;
        qstar[b * 128 + 64 + l] = tot / (asum + 1e-16f);
    }
}

extern "C" void kernel_launch(void* const* d_in, const int* in_sizes, int n_in,
                              void* d_out, int out_size, void* d_ws, size_t ws_size,
                              hipStream_t stream) {
    const float* x      = (const float*)d_in[0];
    const int*   ei     = (const int*)  d_in[1];
    const int*   batch  = (const int*)  d_in[2];
    const float* lin0_w = (const float*)d_in[3];
    const float* lin0_b = (const float*)d_in[4];
    const float* nn1_w  = (const float*)d_in[5];
    const float* nn1_b  = (const float*)d_in[6];
    const float* nn2_w  = (const float*)d_in[7];
    const float* nn2_b  = (const float*)d_in[8];
    const float* conv_b = (const float*)d_in[9];
    const float* gwih   = (const float*)d_in[10];
    const float* gwhh   = (const float*)d_in[11];
    const float* gbih   = (const float*)d_in[12];
    const float* gbhh   = (const float*)d_in[13];
    const float* lwih   = (const float*)d_in[14];
    const float* lwhh   = (const float*)d_in[15];
    const float* lbih   = (const float*)d_in[16];
    const float* lbhh   = (const float*)d_in[17];

    float* qstar = (float*)d_out;                 // [256*128]
    float* h     = (float*)d_out + NGB * 128;     // [N*64] == feat_map

    float* ws     = (float*)d_ws;
    float* W      = ws;                         // 4096
    float* agg    = ws + 4096;                  // N*64
    float* deg    = agg + NN * 64;              // N
    int*   cnt    = (int*)(deg + NN);           // 256
    int*   starts = cnt + 256;                  // 256
    float* hl     = (float*)(starts + 256);     // 256*64
    float* cl     = hl + NGB * 64;              // 256*64
    float* wihT   = cl + NGB * 64;              // 128*256
    float* whhT   = wihT + 128 * 256;           // 64*256
    unsigned int* P = (unsigned int*)(whhT + 64 * 256);  // 14336
    float* brz    = (float*)(P + 14336);        // 128

    hipMemsetAsync(deg, 0, NN * sizeof(float), stream);
    hipMemsetAsync(agg, 0, NN * 64 * sizeof(float), stream);   // once; k_update re-zeroes

    k_precompute_W<<<16, 256, 0, stream>>>(nn1_w, nn1_b, nn2_w, nn2_b, W);
    k_pack_mfma<<<56, 256, 0, stream>>>(W, gwih, gwhh, gbih, gbhh, P, brz);
    k_transpose_lstm<<<128, 256, 0, stream>>>(lwih, lwhh, wihT, whhT);
    k_deg<<<(NE + 255) / 256, 256, 0, stream>>>(ei, deg);
    k_bounds<<<1, 256, 0, stream>>>(batch, starts, cnt);
    k_lin0<<<512, 256, 0, stream>>>(x, lin0_w, lin0_b, h);

    for (int it = 0; it < 3; ++it) {
        k_scatter<<<(NE * 64 + 255) / 256, 256, 0, stream>>>(ei, h, agg);
        k_update<<<782, 256, 0, stream>>>(agg, deg, P, conv_b, brz, gbih, gbhh, h, agg);
    }
    for (int st = 0; st < 3; ++st) {
        k_s2s<<<NGB, 256, 0, stream>>>(h, starts, cnt, wihT, whhT, lbih, lbhh,
                                       hl, cl, qstar, st == 0 ? 1 : 0);
    }
}

// Round 11
// 279.556 us; speedup vs baseline: 3.9111x; 1.2277x over previous
//
#include <hip/hip_runtime.h>
#include <math.h>

#define NN 50000
#define NE 60000
#define FIN 32
#define DIM 64
#define NGB 256   // graphs in batch

typedef short s8v __attribute__((ext_vector_type(8)));
typedef float f4v __attribute__((ext_vector_type(4)));

__device__ __forceinline__ float rl(float v, int lane) {
    return __int_as_float(__builtin_amdgcn_readlane(__float_as_int(v), lane));
}
__device__ __forceinline__ float sigm(float x) { return 1.f / (1.f + expf(-x)); }

// pack two f32 as bf16 (RTN-even) into one u32: a -> low16, b -> high16
__device__ __forceinline__ unsigned int pk2(float a, float b) {
    unsigned int ua = __float_as_uint(a);
    unsigned int ub = __float_as_uint(b);
    ua = (ua + 0x7FFFu + ((ua >> 16) & 1u)) >> 16;
    ub = (ub + 0x7FFFu + ((ub >> 16) & 1u)) & 0xFFFF0000u;
    return ua | ub;
}
__device__ __forceinline__ unsigned short pk1(float a) {
    unsigned int ua = __float_as_uint(a);
    return (unsigned short)((ua + 0x7FFFu + ((ua >> 16) & 1u)) >> 16);
}
__device__ __forceinline__ s8v as_s8(uint4 u) {
    union { uint4 a; s8v b; } c; c.a = u; return c.b;
}

// ---------------- precompute: W[i*64+o] = (relu(nn1_w + nn1_b) @ nn2_w^T + nn2_b)
__global__ void k_precompute_W(const float* __restrict__ nn1_w, const float* __restrict__ nn1_b,
                               const float* __restrict__ nn2_w, const float* __restrict__ nn2_b,
                               float* __restrict__ W) {
    __shared__ float t[64];
    int tid = threadIdx.x;
    if (tid < 64) t[tid] = fmaxf(nn1_w[tid] + nn1_b[tid], 0.f);
    __syncthreads();
    int k = blockIdx.x * blockDim.x + tid;   // 0..4095
    float acc = nn2_b[k];
    #pragma unroll
    for (int j = 0; j < 64; ++j) acc += t[j] * nn2_w[k * 64 + j];
    W[k] = acc;
}

// ---------------- pack weights into MFMA B-fragment layouts (bf16, XOR-swizzled)
// Regions in P (u32 index):
//   [0,2048)      WpA : W as B[k=0..63][col=0..63], col stride 128 B
//   [2048,10240)  B01 : [wih_r|z ; whh_r|z] as B[k=0..127][col=0..127], col stride 256 B
//   [10240,12288) BnI : wih_n as B[k][col], col stride 128 B
//   [12288,14336) BnH : whh_n as B[k][col], col stride 128 B
// Within a col's row, 16B slot at byte kk*2 stored at (kk*2) ^ ((col&7)<<4).
__global__ void k_pack_mfma(const float* __restrict__ W, const float* __restrict__ wih,
                            const float* __restrict__ whh, const float* __restrict__ bih,
                            const float* __restrict__ bhh, unsigned int* __restrict__ P,
                            float* __restrict__ brz) {
    int q = blockIdx.x * 256 + threadIdx.x;   // 56*256 = 14336
    if (q < 128) brz[q] = bih[q] + bhh[q];    // summed r,z biases
    if (q < 2048) {                           // WpA
        int byte = q * 4, col = byte >> 7, rem = byte & 127;
        int lin = rem ^ ((col & 7) << 4);
        int k0 = (lin >> 4) * 8 + ((lin >> 2) & 3) * 2;
        P[q] = pk2(W[k0 * 64 + col], W[(k0 + 1) * 64 + col]);
    } else if (q < 10240) {                   // B01 (K=128)
        int w = q - 2048, byte = w * 4, col = byte >> 8, rem = byte & 255;
        int lin = rem ^ ((col & 7) << 4);
        int k0 = (lin >> 4) * 8 + ((lin >> 2) & 3) * 2;
        int g = col >> 6, o = col & 63;
        int rowbase = (g * 64 + o) * 64;
        const float* src = (k0 >= 64) ? whh : wih;
        int kk = (k0 >= 64) ? k0 - 64 : k0;
        P[q] = pk2(src[rowbase + kk], src[rowbase + kk + 1]);
    } else if (q < 12288) {                   // BnI
        int w = q - 10240, byte = w * 4, col = byte >> 7, rem = byte & 127;
        int lin = rem ^ ((col & 7) << 4);
        int k0 = (lin >> 4) * 8 + ((lin >> 2) & 3) * 2;
        P[q] = pk2(wih[(128 + col) * 64 + k0], wih[(128 + col) * 64 + k0 + 1]);
    } else {                                  // BnH
        int w = q - 12288, byte = w * 4, col = byte >> 7, rem = byte & 127;
        int lin = rem ^ ((col & 7) << 4);
        int k0 = (lin >> 4) * 8 + ((lin >> 2) & 3) * 2;
        P[q] = pk2(whh[(128 + col) * 64 + k0], whh[(128 + col) * 64 + k0 + 1]);
    }
}

// ---------------- transpose LSTM weights for coalesced gate dots
__global__ void k_transpose_lstm(const float* __restrict__ wih, const float* __restrict__ whh,
                                 float* __restrict__ wihT, float* __restrict__ whhT) {
    int p = blockIdx.x * 256 + threadIdx.x;
    if (p < 256 * 128) { int o = p >> 7, k = p & 127; wihT[k * 256 + o] = wih[p]; }
    if (p < 256 * 64)  { int o = p >> 6, k = p & 63;  whhT[k * 256 + o] = whh[p]; }
}

// ---------------- degree over dst (edge atomics only; low contention)
__global__ void k_deg(const int* __restrict__ ei, float* __restrict__ deg) {
    int i = blockIdx.x * 256 + threadIdx.x;
    if (i < NE) atomicAdd(&deg[ei[NE + i]], 1.0f);
}

// ---------------- per-graph starts/cnt via binary search on sorted batch (no atomics)
__global__ void k_bounds(const int* __restrict__ batch, int* __restrict__ starts,
                         int* __restrict__ cnt) {
    __shared__ int sLB[257];
    int b = threadIdx.x;   // 0..255
    int lo = 0, hi = NN;
    while (lo < hi) {      // lower_bound(batch, b)
        int mid = (lo + hi) >> 1;
        if (batch[mid] < b) lo = mid + 1; else hi = mid;
    }
    sLB[b] = lo;
    if (b == 0) sLB[256] = NN;
    __syncthreads();
    starts[b] = sLB[b];
    cnt[b] = sLB[b + 1] - sLB[b];
}

// ---------------- lin0: h = relu(x @ lin0_w^T + b); grid-stride, weights staged ONCE
// per block (512 blocks). 1 wave = 1 node per iteration, 2-node unroll for ILP.
__global__ void k_lin0(const float* __restrict__ x, const float* __restrict__ w,
                       const float* __restrict__ b, float* __restrict__ h) {
    __shared__ float wT[FIN * 64];   // wT[k*64+o] = w[o*32+k]
    int tid = threadIdx.x;
    for (int p = tid; p < FIN * 64; p += 256) {
        int k = p >> 6, o = p & 63;          // linear LDS write, strided L2-hit read
        wT[p] = w[o * FIN + k];
    }
    __syncthreads();
    int l = tid & 63;
    float bl = b[l];
    int wave = blockIdx.x * 4 + (tid >> 6);
    int nwaves = gridDim.x * 4;
    for (int n0 = wave * 2; n0 < NN; n0 += nwaves * 2) {   // NN even: both nodes valid
        float xv0 = x[n0 * FIN + (l & 31)];
        float xv1 = x[(n0 + 1) * FIN + (l & 31)];
        float a0 = bl, a1 = bl;
        #pragma unroll
        for (int k = 0; k < FIN; ++k) {
            float wk = wT[k * 64 + l];
            a0 += rl(xv0, k) * wk;
            a1 += rl(xv1, k) * wk;
        }
        h[n0 * 64 + l] = fmaxf(a0, 0.f);
        h[(n0 + 1) * 64 + l] = fmaxf(a1, 0.f);
    }
}

// ---------------- scatter: agg[dst] += h[src]  (64 lanes per edge)
__global__ void k_scatter(const int* __restrict__ ei, const float* __restrict__ h,
                          float* __restrict__ agg) {
    int gid = blockIdx.x * 256 + threadIdx.x;
    int e = gid >> 6, l = gid & 63;
    if (e >= NE) return;
    int s = ei[e], d = ei[NE + e];
    atomicAdd(&agg[d * 64 + l], h[s * 64 + l]);
}

// ---------------- MFMA conv(W)+GRU node update. Wave = 16 nodes, block = 4 waves.
// LDS: 56 KB pre-packed bf16 weights (straight copy) + 4 x 2 KB per-wave m-transpose.
// Re-zeroes agg after reading (each element exactly once).
__global__ void __launch_bounds__(256) k_update(
    const float* __restrict__ agg, const float* __restrict__ deg,
    const unsigned int* __restrict__ P, const float* __restrict__ conv_b,
    const float* __restrict__ brz, const float* __restrict__ bih, const float* __restrict__ bhh,
    float* __restrict__ h, float* __restrict__ aggz) {
    __shared__ unsigned int L[16384];   // 64 KB
    int tid = threadIdx.x;
    #pragma unroll
    for (int p = 0; p < 14336; p += 256) L[p + tid] = P[p + tid];
    __syncthreads();

    int l = tid & 63;
    int w = tid >> 6;
    int nb = (blockIdx.x * 4 + w) * 16;
    if (nb >= NN) return;               // idle waves in last block (after barrier)
    int row = l & 15, kq = l >> 4;      // A/B frag: row/col = lane&15, k-chunk = lane>>4
    int node = nb + row;

    float dv = deg[node];
    float inv = dv > 0.f ? 1.f / dv : 0.f;

    // ---- A-frags of agg_mean (bf16), zero agg behind us
    uint4 aA[2];
    #pragma unroll
    for (int kt = 0; kt < 2; ++kt) {
        const float4* src = (const float4*)(agg + node * 64 + kt * 32 + kq * 8);
        float4 x0 = src[0], x1 = src[1];
        float4 z4 = {0.f, 0.f, 0.f, 0.f};
        ((float4*)(aggz + node * 64 + kt * 32 + kq * 8))[0] = z4;
        ((float4*)(aggz + node * 64 + kt * 32 + kq * 8))[1] = z4;
        aA[kt].x = pk2(x0.x * inv, x0.y * inv);
        aA[kt].y = pk2(x0.z * inv, x0.w * inv);
        aA[kt].z = pk2(x1.x * inv, x1.y * inv);
        aA[kt].w = pk2(x1.z * inv, x1.w * inv);
    }

    // ---- stage A: m = relu(aggmean @ W + conv_b)
    f4v mC[4];
    #pragma unroll
    for (int ct = 0; ct < 4; ++ct) {
        f4v acc = {0.f, 0.f, 0.f, 0.f};
        int col = ct * 16 + row;
        #pragma unroll
        for (int kt = 0; kt < 2; ++kt) {
            int boff = col * 128 + ((kt * 64 + kq * 16) ^ ((col & 7) << 4));
            uint4 b = *(const uint4*)((const char*)L + boff);
            acc = __builtin_amdgcn_mfma_f32_16x16x32_bf16(as_s8(aA[kt]), as_s8(b), acc, 0, 0, 0);
        }
        mC[ct] = acc;
    }

    // ---- transpose m to A-frag layout via per-wave LDS region (swizzled)
    int mbase = 57344 + w * 2048;
    #pragma unroll
    for (int ct = 0; ct < 4; ++ct) {
        int ch = ct * 16 + row;
        float cb = conv_b[ch];
        #pragma unroll
        for (int r = 0; r < 4; ++r) {
            float mval = fmaxf(mC[ct][r] + cb, 0.f);
            int nrow = kq * 4 + r;
            int off = mbase + ((nrow * 128 + ch * 2) ^ ((nrow & 7) << 4));
            *(unsigned short*)((char*)L + off) = pk1(mval);
        }
    }
    // same-wave DS ordering: reads below see the writes above (no block barrier needed)
    uint4 mA[2], hA[2];
    #pragma unroll
    for (int kt = 0; kt < 2; ++kt) {
        int off = mbase + ((row * 128 + kt * 64 + kq * 16) ^ ((row & 7) << 4));
        mA[kt] = *(const uint4*)((const char*)L + off);
        const float4* hs = (const float4*)(h + node * 64 + kt * 32 + kq * 8);
        float4 y0 = hs[0], y1 = hs[1];
        hA[kt].x = pk2(y0.x, y0.y);
        hA[kt].y = pk2(y0.z, y0.w);
        hA[kt].z = pk2(y1.x, y1.y);
        hA[kt].w = pk2(y1.z, y1.w);
    }

    // ---- gates r,z: [m|h](16x128) @ B01(128x128)
    f4v g01[8];
    #pragma unroll
    for (int ct = 0; ct < 8; ++ct) {
        f4v acc = {0.f, 0.f, 0.f, 0.f};
        int col = ct * 16 + row;
        #pragma unroll
        for (int kt = 0; kt < 4; ++kt) {
            uint4 a = (kt < 2) ? mA[kt] : hA[kt - 2];
            int boff = 8192 + col * 256 + ((kt * 64 + kq * 16) ^ ((col & 7) << 4));
            uint4 b = *(const uint4*)((const char*)L + boff);
            acc = __builtin_amdgcn_mfma_f32_16x16x32_bf16(as_s8(a), as_s8(b), acc, 0, 0, 0);
        }
        g01[ct] = acc;
    }
    // ---- i_n = m @ wih_n^T ; h_n = h @ whh_n^T
    f4v gin[4], ghn[4];
    #pragma unroll
    for (int ct = 0; ct < 4; ++ct) {
        f4v ai = {0.f, 0.f, 0.f, 0.f}, ah = {0.f, 0.f, 0.f, 0.f};
        int col = ct * 16 + row;
        #pragma unroll
        for (int kt = 0; kt < 2; ++kt) {
            int swz = (kt * 64 + kq * 16) ^ ((col & 7) << 4);
            uint4 bi = *(const uint4*)((const char*)L + 40960 + col * 128 + swz);
            uint4 bh = *(const uint4*)((const char*)L + 49152 + col * 128 + swz);
            ai = __builtin_amdgcn_mfma_f32_16x16x32_bf16(as_s8(mA[kt]), as_s8(bi), ai, 0, 0, 0);
            ah = __builtin_amdgcn_mfma_f32_16x16x32_bf16(as_s8(hA[kt]), as_s8(bh), ah, 0, 0, 0);
        }
        gin[ct] = ai; ghn[ct] = ah;
    }

    // ---- epilogue: GRU cell in C-frag layout (col=lane&15, row=(lane>>4)*4+r)
    #pragma unroll
    for (int ct = 0; ct < 4; ++ct) {
        int ch = ct * 16 + row;
        float br = brz[ch], bz = brz[64 + ch];
        float bin = bih[128 + ch], bhn = bhh[128 + ch];
        #pragma unroll
        for (int r = 0; r < 4; ++r) {
            int n2 = nb + kq * 4 + r;
            float rg = sigm(g01[ct][r] + br);
            float zg = sigm(g01[4 + ct][r] + bz);
            float ng = tanhf(gin[ct][r] + bin + rg * (ghn[ct][r] + bhn));
            float hold = h[n2 * 64 + ch];
            h[n2 * 64 + ch] = (1.f - zg) * ng + zg * hold;
        }
    }
}

// ---------------- fused Set2Set step: LSTM + ONLINE segment softmax + weighted sum.
// One block of 16 waves per graph; single pass over h (flash-style m/ss/racc).
__global__ void __launch_bounds__(1024) k_s2s(
    const float* __restrict__ h, const int* __restrict__ starts,
    const int* __restrict__ cnt, const float* __restrict__ wihT,
    const float* __restrict__ whhT, const float* __restrict__ bih,
    const float* __restrict__ bhh, float* __restrict__ hl,
    float* __restrict__ cl, float* __restrict__ qstar, int first) {
    __shared__ float ga[256];
    __shared__ float hlv[64];
    __shared__ float mw[16], ssw[16];
    __shared__ float accw[16][64];
    int b = blockIdx.x, tid = threadIdx.x, w = tid >> 6, l = tid & 63;

    // ---- LSTM cell (tid<256 active; barriers block-wide)
    if (first) {
        if (tid < 64) {   // q_star = 0, hl = 0, cl = 0 -> gates are biases only
            float ig = sigm(bih[tid] + bhh[tid]);
            float gg = tanhf(bih[128 + tid] + bhh[128 + tid]);
            float og = sigm(bih[192 + tid] + bhh[192 + tid]);
            float c = ig * gg;
            cl[b * 64 + tid] = c;
            float hh = og * tanhf(c);
            hl[b * 64 + tid] = hh;
            hlv[tid] = hh;
        }
    } else {
        if (tid < 256) {
            const float* qs = qstar + b * 128;
            const float* hb = hl + b * 64;
            float a = bih[tid] + bhh[tid];
            for (int k = 0; k < 128; ++k) a += qs[k] * wihT[k * 256 + tid];
            for (int k = 0; k < 64; ++k)  a += hb[k] * whhT[k * 256 + tid];
            ga[tid] = a;
        }
        __syncthreads();
        if (tid < 64) {
            float c = sigm(ga[64 + tid]) * cl[b * 64 + tid] + sigm(ga[tid]) * tanhf(ga[128 + tid]);
            cl[b * 64 + tid] = c;
            float hh = sigm(ga[192 + tid]) * tanhf(c);
            hl[b * 64 + tid] = hh;
            hlv[tid] = hh;
        }
    }
    __syncthreads();

    int s = starts[b], c = cnt[b];
    float hld = hlv[l];
    // ---- single pass: online softmax + weighted sum (wave-striped over nodes)
    float m = -1e30f, ss = 0.f, racc = 0.f;
    for (int i = w; i < c; i += 16) {
        float hv = h[(s + i) * 64 + l];
        float v = hv * hld;
        #pragma unroll
        for (int off = 32; off; off >>= 1) v += __shfl_xor(v, off, 64);
        float nm = fmaxf(m, v);
        float scale = expf(m - nm);     // 0 on first hit (m=-1e30), 1 if no new max
        float p = expf(v - nm);
        ss = ss * scale + p;
        racc = racc * scale + p * hv;
        m = nm;
    }
    if (l == 0) { mw[w] = m; ssw[w] = ss; }
    accw[w][l] = racc;
    __syncthreads();
    // ---- combine 16 waves (tid<64: lane l = channel l)
    if (tid < 64) {
        float M = -1e30f;
        #pragma unroll
        for (int q = 0; q < 16; ++q) M = fmaxf(M, mw[q]);
        float asum = 0.f, r = 0.f;
        #pragma unroll
        for (int q = 0; q < 16; ++q) {
            float f = expf(mw[q] - M);   // 0 for empty waves when M finite
            asum += ssw[q] * f;
            r += accw[q][tid] * f;
        }
        qstar[b * 128 + tid] = hlv[tid];
        qstar[b * 128 + 64 + tid] = r / (asum + 1e-16f);
    }
}

extern "C" void kernel_launch(void* const* d_in, const int* in_sizes, int n_in,
                              void* d_out, int out_size, void* d_ws, size_t ws_size,
                              hipStream_t stream) {
    const float* x      = (const float*)d_in[0];
    const int*   ei     = (const int*)  d_in[1];
    const int*   batch  = (const int*)  d_in[2];
    const float* lin0_w = (const float*)d_in[3];
    const float* lin0_b = (const float*)d_in[4];
    const float* nn1_w  = (const float*)d_in[5];
    const float* nn1_b  = (const float*)d_in[6];
    const float* nn2_w  = (const float*)d_in[7];
    const float* nn2_b  = (const float*)d_in[8];
    const float* conv_b = (const float*)d_in[9];
    const float* gwih   = (const float*)d_in[10];
    const float* gwhh   = (const float*)d_in[11];
    const float* gbih   = (const float*)d_in[12];
    const float* gbhh   = (const float*)d_in[13];
    const float* lwih   = (const float*)d_in[14];
    const float* lwhh   = (const float*)d_in[15];
    const float* lbih   = (const float*)d_in[16];
    const float* lbhh   = (const float*)d_in[17];

    float* qstar = (float*)d_out;                 // [256*128]
    float* h     = (float*)d_out + NGB * 128;     // [N*64] == feat_map

    float* ws     = (float*)d_ws;
    float* W      = ws;                         // 4096
    float* agg    = ws + 4096;                  // N*64
    float* deg    = agg + NN * 64;              // N
    int*   cnt    = (int*)(deg + NN);           // 256
    int*   starts = cnt + 256;                  // 256
    float* hl     = (float*)(starts + 256);     // 256*64
    float* cl     = hl + NGB * 64;              // 256*64
    float* wihT   = cl + NGB * 64;              // 128*256
    float* whhT   = wihT + 128 * 256;           // 64*256
    unsigned int* P = (unsigned int*)(whhT + 64 * 256);  // 14336
    float* brz    = (float*)(P + 14336);        // 128

    hipMemsetAsync(deg, 0, NN * sizeof(float), stream);
    hipMemsetAsync(agg, 0, NN * 64 * sizeof(float), stream);   // once; k_update re-zeroes

    k_precompute_W<<<16, 256, 0, stream>>>(nn1_w, nn1_b, nn2_w, nn2_b, W);
    k_pack_mfma<<<56, 256, 0, stream>>>(W, gwih, gwhh, gbih, gbhh, P, brz);
    k_transpose_lstm<<<128, 256, 0, stream>>>(lwih, lwhh, wihT, whhT);
    k_deg<<<(NE + 255) / 256, 256, 0, stream>>>(ei, deg);
    k_bounds<<<1, 256, 0, stream>>>(batch, starts, cnt);
    k_lin0<<<512, 256, 0, stream>>>(x, lin0_w, lin0_b, h);

    for (int it = 0; it < 3; ++it) {
        k_scatter<<<(NE * 64 + 255) / 256, 256, 0, stream>>>(ei, h, agg);
        k_update<<<782, 256, 0, stream>>>(agg, deg, P, conv_b, brz, gbih, gbhh, h, agg);
    }
    for (int st = 0; st < 3; ++st) {
        k_s2s<<<NGB, 1024, 0, stream>>>(h, starts, cnt, wihT, whhT, lbih, lbhh,
                                        hl, cl, qstar, st == 0 ? 1 : 0);
    }
}